// Round 14
// baseline (285.592 us; speedup 1.0000x reference)
//
#include <hip/hip_runtime.h>

#define FDIM 128
#define LN_EPS 1e-5f
#define BSH 9              // 512 nodes per bucket
#define EPB 2048           // edges per block in bucket passes

typedef short short8 __attribute__((ext_vector_type(8)));
typedef float f32x4 __attribute__((ext_vector_type(4)));

__device__ __forceinline__ ushort f2bf(float f) {
    uint u = __float_as_uint(f);
    u += 0x7fff + ((u >> 16) & 1);      // RNE
    return (ushort)(u >> 16);
}
__device__ __forceinline__ float bflo(uint u) { return __uint_as_float(u << 16); }
__device__ __forceinline__ float bfhi(uint u) { return __uint_as_float(u & 0xffff0000u); }
__device__ __forceinline__ float bfs(short s) { return __uint_as_float(((uint)(ushort)s) << 16); }

// ---------------- bucketed CSR build (no global atomics) — proven R12 ----------------
__global__ __launch_bounds__(256) void k_bcount(const int* __restrict__ dst,
                                                uint* __restrict__ mat, int nbk, int E) {
    __shared__ uint cnt[512];
    int t = threadIdx.x;
    for (int i = t; i < nbk; i += 256) cnt[i] = 0;
    __syncthreads();
    int base = blockIdx.x * EPB, end = min(base + EPB, E);
    for (int e = base + t; e < end; e += 256)
        atomicAdd(&cnt[(uint)dst[e] >> BSH], 1u);
    __syncthreads();
    for (int i = t; i < nbk; i += 256) mat[(size_t)blockIdx.x * nbk + i] = cnt[i];
}

__global__ __launch_bounds__(1024) void k_colscan(uint* __restrict__ mat,
                                                  uint* __restrict__ btot, int nbk, int nblk) {
    __shared__ uint s[1024];
    int b = blockIdx.x, t = threadIdx.x;
    uint run = 0;
    for (int base = 0; base < nblk; base += 1024) {
        int i = base + t;
        uint v = (i < nblk) ? mat[(size_t)i * nbk + b] : 0;
        s[t] = v;
        __syncthreads();
        for (int off = 1; off < 1024; off <<= 1) {
            uint u = (t >= off) ? s[t - off] : 0;
            __syncthreads();
            s[t] += u;
            __syncthreads();
        }
        if (i < nblk) mat[(size_t)i * nbk + b] = run + s[t] - v;
        run += s[1023];
        __syncthreads();
    }
    if (t == 0) btot[b] = run;
}

__global__ __launch_bounds__(256) void k_bscatter(const int* __restrict__ src,
                                                  const int* __restrict__ dst,
                                                  const uint* __restrict__ mat,
                                                  const uint* __restrict__ btot,
                                                  uint* __restrict__ ebuf, int nbk, int E) {
    __shared__ uint cur[512];
    __shared__ uint ps[256];
    int t = threadIdx.x;
    uint v = (t < nbk) ? btot[t] : 0;
    ps[t] = v;
    __syncthreads();
    for (int off = 1; off < 256; off <<= 1) {
        uint u = (t >= off) ? ps[t - off] : 0;
        __syncthreads();
        ps[t] += u;
        __syncthreads();
    }
    if (t < nbk) cur[t] = (ps[t] - v) + mat[(size_t)blockIdx.x * nbk + t];
    __syncthreads();
    int base = blockIdx.x * EPB, end = min(base + EPB, E);
    for (int e = base + t; e < end; e += 256) {
        uint d = (uint)dst[e];
        uint off = atomicAdd(&cur[d >> BSH], 1u);
        ebuf[off] = ((d & 511u) << 17) | (uint)src[e];
    }
}

__global__ __launch_bounds__(256) void k_bdeg(const uint* __restrict__ ebuf,
                                              const uint* __restrict__ btot,
                                              int* __restrict__ deg, float* __restrict__ dinv,
                                              uint* __restrict__ padtot, int N, int nbk) {
    __shared__ uint cnt[512];
    __shared__ uint ps[256];
    __shared__ uint begs;
    int b = blockIdx.x, t = threadIdx.x;
    for (int i = t; i < 512; i += 256) cnt[i] = 0;
    uint v = (t < nbk) ? btot[t] : 0;
    ps[t] = v;
    __syncthreads();
    for (int off = 1; off < 256; off <<= 1) {
        uint u = (t >= off) ? ps[t - off] : 0;
        __syncthreads();
        ps[t] += u;
        __syncthreads();
    }
    if (t == b) begs = ps[t] - v;
    __syncthreads();
    uint beg = begs, cn = btot[b];
    for (uint i = t; i < cn; i += 256) atomicAdd(&cnt[ebuf[beg + i] >> 17], 1u);
    __syncthreads();
    int n0 = b << BSH;
    uint loc = 0;
    for (int i = t; i < 512; i += 256) {
        int n = n0 + i;
        if (n < N) {
            uint dg = cnt[i];
            deg[n] = (int)dg;
            dinv[n] = rsqrtf((float)dg + 1.0f);
            loc += (dg + 7u) & ~7u;
        }
    }
    ps[t] = loc;
    __syncthreads();
    for (int off = 128; off >= 1; off >>= 1) {
        if (t < off) ps[t] += ps[t + off];
        __syncthreads();
    }
    if (t == 0) padtot[b] = ps[0];
}

__device__ __forceinline__ void bfill_body(const uint* __restrict__ ebuf,
                                           const uint* __restrict__ btot,
                                           const uint* __restrict__ padtot,
                                           const int* __restrict__ deg,
                                           int* __restrict__ rowptr, int* __restrict__ col,
                                           int N, int nbk, int b) {
    __shared__ uint ps[256];
    __shared__ uint curf[512];
    __shared__ uint sc0, sc1;
    int t = threadIdx.x;
    uint v = (t < nbk) ? btot[t] : 0;
    ps[t] = v;
    __syncthreads();
    for (int off = 1; off < 256; off <<= 1) {
        uint u = (t >= off) ? ps[t - off] : 0;
        __syncthreads();
        ps[t] += u;
        __syncthreads();
    }
    if (t == b) sc0 = ps[t] - v;
    __syncthreads();
    uint w = (t < nbk) ? padtot[t] : 0;
    ps[t] = w;
    __syncthreads();
    for (int off = 1; off < 256; off <<= 1) {
        uint u = (t >= off) ? ps[t - off] : 0;
        __syncthreads();
        ps[t] += u;
        __syncthreads();
    }
    if (t == b) sc1 = ps[t] - w;
    if (b == nbk - 1 && t == nbk - 1) rowptr[N] = (int)ps[t];
    __syncthreads();
    uint beg = sc0, cn = btot[b], base = sc1;
    int n0 = b << BSH;
    int nA = n0 + 2 * t, nB = nA + 1;
    uint dA = (nA < N) ? (uint)deg[nA] : 0;
    uint dB = (nB < N) ? (uint)deg[nB] : 0;
    uint pA = (dA + 7u) & ~7u, pB = (dB + 7u) & ~7u;
    uint pair = pA + pB;
    ps[t] = pair;
    __syncthreads();
    for (int off = 1; off < 256; off <<= 1) {
        uint u = (t >= off) ? ps[t - off] : 0;
        __syncthreads();
        ps[t] += u;
        __syncthreads();
    }
    uint pex = ps[t] - pair;
    uint rA = base + pex, rB = rA + pA;
    curf[2 * t] = rA; curf[2 * t + 1] = rB;
    if (nA < N) rowptr[nA] = (int)rA;
    if (nB < N) rowptr[nB] = (int)rB;
    if (nA < N) for (uint k = dA; k < pA; ++k) col[rA + k] = N;
    if (nB < N) for (uint k = dB; k < pB; ++k) col[rB + k] = N;
    __syncthreads();
    for (uint i = t; i < cn; i += 256) {
        uint e = ebuf[beg + i];
        uint p = atomicAdd(&curf[e >> 17], 1u);
        col[p] = (int)(e & 0x1FFFFu);
    }
}

// -------- weights -> W^T bf16 + zero sentinel rows (row N of each H slice) --------
__global__ void k_wt2(const float* __restrict__ W1, const float* __restrict__ W2,
                      ushort* __restrict__ WT1, ushort* __restrict__ WT2,
                      ushort* __restrict__ H, int N) {
    int b = blockIdx.x, k = threadIdx.x;
    if (b < 128)      WT1[b * 128 + k] = f2bf(W1[k * 128 + b]);
    else if (b < 256) WT2[(b - 128) * 128 + k] = f2bf(W2[k * 128 + (b - 128)]);
    else if (k < 64) {                      // 8 slices x 16 ushorts = 64 uints
        int s = k >> 3, j = k & 7;
        ((uint*)(H + (size_t)s * (N + 1) * 16 + (size_t)N * 16))[j] = 0;
    }
}

// -------- GEMM: H'[slice][r][16] = dinv[r]*(X[r,:]@W), slice-major bf16 out --------
// MODE 0: X = fp32 rows.  MODE 1: X = sliced bf16 A + fused LayerNorm (stats,gamma,beta).
template <int MODE>
__device__ __forceinline__ void gemm_body(char* sXb, char* sWb,
                                          const void* __restrict__ Xin,
                                          const ushort* __restrict__ WT,
                                          const float* __restrict__ dinv,
                                          const float2* __restrict__ stats,
                                          const float* __restrict__ gamma,
                                          const float* __restrict__ beta,
                                          ushort* __restrict__ H, int N, int bid) {
    int t = threadIdx.x;
    int w = t >> 6, lane = t & 63;
    int cl = lane & 15, kq = lane >> 4;
    int base = bid * 64;

    const short8* Wg = (const short8*)WT;
#pragma unroll
    for (int k = 0; k < 8; ++k) {
        int idx = t + k * 256;
        int c = idx >> 4, ch = idx & 15;
        *(short8*)(sWb + c * 256 + ((ch * 16) ^ ((c & 7) << 4))) = Wg[idx];
    }

    if constexpr (MODE == 0) {
        const float4* X4 = (const float4*)Xin;
        size_t lim = (size_t)N * 32 - 1;
#pragma unroll
        for (int k = 0; k < 8; ++k) {
            int idx = t + k * 256;
            size_t gi = (size_t)base * 32 + idx;
            float4 v = X4[gi < lim ? gi : lim];
            ushort4 o;
            o.x = f2bf(v.x); o.y = f2bf(v.y); o.z = f2bf(v.z); o.w = f2bf(v.w);
            int row = idx >> 5, b8 = (idx & 31) * 8;
            *(ushort4*)(sXb + row * 256 + (b8 ^ ((row & 7) << 4))) = o;
        }
    } else {
        const short8* A8 = (const short8*)Xin;          // sliced: [slice][(N+1) rows][2 short8]
        size_t srows = (size_t)(N + 1) * 2;
#pragma unroll
        for (int k = 0; k < 4; ++k) {
            int idx = t + k * 256;                      // 64 rows x 16 chunks
            int row = idx >> 4, cc = idx & 15;
            int rc = min(base + row, N - 1);
            short8 v = A8[(size_t)(cc >> 1) * srows + (size_t)rc * 2 + (cc & 1)];
            float2 ms = stats[rc];
            short8 o;
#pragma unroll
            for (int j = 0; j < 8; ++j) {
                int f = cc * 8 + j;
                float val = (bfs(v[j]) - ms.x) * ms.y * gamma[f] + beta[f];
                o[j] = (short)f2bf(val);
            }
            *(short8*)(sXb + row * 256 + ((cc * 16) ^ ((row & 7) << 4))) = o;
        }
    }
    __syncthreads();

    int rl = w * 16 + cl;
    short8 b0, b1, b2, b3;
#pragma unroll
    for (int kt = 0; kt < 4; ++kt) {
        short8 v = *(const short8*)(sXb + rl * 256 + ((kt * 64 + kq * 16) ^ ((rl & 7) << 4)));
        if (kt == 0) b0 = v; else if (kt == 1) b1 = v; else if (kt == 2) b2 = v; else b3 = v;
    }

    int r = base + rl;
    bool ok = r < N;
    float di = dinv[min(r, N - 1)];
#pragma unroll
    for (int nt = 0; nt < 8; ++nt) {
        int c = nt * 16 + cl;
        int sw = (c & 7) << 4;
        f32x4 acc = {0.f, 0.f, 0.f, 0.f};
        acc = __builtin_amdgcn_mfma_f32_16x16x32_bf16(
            *(const short8*)(sWb + c * 256 + ((0 * 64 + kq * 16) ^ sw)), b0, acc, 0, 0, 0);
        acc = __builtin_amdgcn_mfma_f32_16x16x32_bf16(
            *(const short8*)(sWb + c * 256 + ((1 * 64 + kq * 16) ^ sw)), b1, acc, 0, 0, 0);
        acc = __builtin_amdgcn_mfma_f32_16x16x32_bf16(
            *(const short8*)(sWb + c * 256 + ((2 * 64 + kq * 16) ^ sw)), b2, acc, 0, 0, 0);
        acc = __builtin_amdgcn_mfma_f32_16x16x32_bf16(
            *(const short8*)(sWb + c * 256 + ((3 * 64 + kq * 16) ^ sw)), b3, acc, 0, 0, 0);
        if (ok) {
            ushort4 o;
            o.x = f2bf(acc[0] * di); o.y = f2bf(acc[1] * di);
            o.z = f2bf(acc[2] * di); o.w = f2bf(acc[3] * di);
            // slice-major: slice nt covers features nt*16..+15
            *(ushort4*)(H + (size_t)nt * (N + 1) * 16 + (size_t)r * 16 + kq * 4) = o;
        }
    }
}

template <int MODE>
__global__ __launch_bounds__(256) void k_gemm(const void* __restrict__ Xin,
                                              const ushort* __restrict__ WT,
                                              const float* __restrict__ dinv,
                                              const float2* __restrict__ stats,
                                              const float* __restrict__ gamma,
                                              const float* __restrict__ beta,
                                              ushort* __restrict__ H, int N) {
    __shared__ ushort sX[64 * 128];
    __shared__ ushort sW[128 * 128];
    gemm_body<MODE>((char*)sX, (char*)sW, Xin, WT, dinv, stats, gamma, beta, H, N, blockIdx.x);
}

// -------- MEGA: blocks [0,ngemm) = gemm1 (fp32 in), blocks [ngemm,ngemm+nbk) = D2 fill --------
__global__ __launch_bounds__(256) void k_mega(const void* __restrict__ Xin,
                                              const ushort* __restrict__ WT,
                                              const float* __restrict__ dinv,
                                              ushort* __restrict__ H, int N, int ngemm,
                                              const uint* __restrict__ ebuf,
                                              const uint* __restrict__ btot,
                                              const uint* __restrict__ padtot,
                                              const int* __restrict__ deg,
                                              int* __restrict__ rowptr,
                                              int* __restrict__ col, int nbk) {
    __shared__ ushort sX[64 * 128];
    __shared__ ushort sW[128 * 128];
    if (blockIdx.x < (uint)ngemm) {
        gemm_body<0>((char*)sX, (char*)sW, Xin, WT, dinv, nullptr, nullptr, nullptr, H, N, blockIdx.x);
    } else {
        bfill_body(ebuf, btot, padtot, deg, rowptr, col, N, nbk, blockIdx.x - ngemm);
    }
}

// ------- sliced aggregate: slice = blockIdx&7 (round-robin XCD alignment), -------
// 4 lanes/node (uint2 = 4 features), bias+ReLU, write sliced A + LN partial sums.
__global__ __launch_bounds__(256) void k_agg_s(const ushort* __restrict__ Hs,
                                               const int* __restrict__ rowptr,
                                               const int* __restrict__ col,
                                               const float* __restrict__ dinv,
                                               const float* __restrict__ bias,
                                               ushort* __restrict__ Aout,
                                               float2* __restrict__ pstat, int N) {
    int s = blockIdx.x & 7;
    int chunk = blockIdx.x >> 3;
    int w = threadIdx.x >> 6, lane = threadIdx.x & 63;
    int g = lane >> 2, fl = lane & 3;       // group of 4 lanes per node
    int node = chunk * 64 + w * 16 + g;
    bool valid = node < N;
    int nodec = valid ? node : N - 1;

    const uint2* Hu = (const uint2*)(Hs + (size_t)s * (N + 1) * 16);   // row = 4 uint2
    float di = dinv[nodec];
    uint2 hv = Hu[(size_t)nodec * 4 + fl];
    float a0 = bflo(hv.x), a1 = bfhi(hv.x), a2 = bflo(hv.y), a3 = bfhi(hv.y);

    int beg = rowptr[nodec];
    int deg8 = rowptr[nodec + 1] - beg;     // multiple of 8
    const int* cp = col + beg;

    for (int i = 0; i < deg8; i += 8) {
        int e0 = cp[i + 0], e1 = cp[i + 1], e2 = cp[i + 2], e3 = cp[i + 3];
        int e4 = cp[i + 4], e5 = cp[i + 5], e6 = cp[i + 6], e7 = cp[i + 7];
        uint2 u0 = Hu[(size_t)e0 * 4 + fl];
        uint2 u1 = Hu[(size_t)e1 * 4 + fl];
        uint2 u2 = Hu[(size_t)e2 * 4 + fl];
        uint2 u3 = Hu[(size_t)e3 * 4 + fl];
        uint2 u4 = Hu[(size_t)e4 * 4 + fl];
        uint2 u5 = Hu[(size_t)e5 * 4 + fl];
        uint2 u6 = Hu[(size_t)e6 * 4 + fl];
        uint2 u7 = Hu[(size_t)e7 * 4 + fl];
        a0 += bflo(u0.x); a1 += bfhi(u0.x); a2 += bflo(u0.y); a3 += bfhi(u0.y);
        a0 += bflo(u1.x); a1 += bfhi(u1.x); a2 += bflo(u1.y); a3 += bfhi(u1.y);
        a0 += bflo(u2.x); a1 += bfhi(u2.x); a2 += bflo(u2.y); a3 += bfhi(u2.y);
        a0 += bflo(u3.x); a1 += bfhi(u3.x); a2 += bflo(u3.y); a3 += bfhi(u3.y);
        a0 += bflo(u4.x); a1 += bfhi(u4.x); a2 += bflo(u4.y); a3 += bfhi(u4.y);
        a0 += bflo(u5.x); a1 += bfhi(u5.x); a2 += bflo(u5.y); a3 += bfhi(u5.y);
        a0 += bflo(u6.x); a1 += bfhi(u6.x); a2 += bflo(u6.y); a3 += bfhi(u6.y);
        a0 += bflo(u7.x); a1 += bfhi(u7.x); a2 += bflo(u7.y); a3 += bfhi(u7.y);
    }

    float4 bb = ((const float4*)bias)[s * 4 + fl];     // features s*16 + fl*4 ..+3
    a0 = fmaxf(fmaf(a0, di, bb.x), 0.f);
    a1 = fmaxf(fmaf(a1, di, bb.y), 0.f);
    a2 = fmaxf(fmaf(a2, di, bb.z), 0.f);
    a3 = fmaxf(fmaf(a3, di, bb.w), 0.f);

    float s1 = (a0 + a1) + (a2 + a3);
    float s2 = (a0 * a0 + a1 * a1) + (a2 * a2 + a3 * a3);
    s1 += __shfl_xor(s1, 1); s1 += __shfl_xor(s1, 2);  // 4-lane group reduce
    s2 += __shfl_xor(s2, 1); s2 += __shfl_xor(s2, 2);

    if (!valid) return;
    uint2 o;
    o.x = (uint)f2bf(a0) | ((uint)f2bf(a1) << 16);
    o.y = (uint)f2bf(a2) | ((uint)f2bf(a3) << 16);
    ((uint2*)(Aout + (size_t)s * (N + 1) * 16))[(size_t)node * 4 + fl] = o;
    if (fl == 0) pstat[(size_t)node * 8 + s] = make_float2(s1, s2);
}

// per-node LN stats from 8 slice partials
__global__ void k_lnstat(const float2* __restrict__ pstat, float2* __restrict__ stats, int N) {
    int i = blockIdx.x * 256 + threadIdx.x;
    if (i < N) {
        float s1 = 0.f, s2 = 0.f;
#pragma unroll
        for (int s = 0; s < 8; ++s) {
            float2 p = pstat[(size_t)i * 8 + s];
            s1 += p.x; s2 += p.y;
        }
        float mu = s1 * (1.f / 128.f);
        float var = s2 * (1.f / 128.f) - mu * mu;
        stats[i] = make_float2(mu, rsqrtf(var + LN_EPS));
    }
}

// final LN apply: sliced bf16 A2 -> fp32 [node][128]
__global__ void k_lnapply(const ushort* __restrict__ A, const float2* __restrict__ stats,
                          const float* __restrict__ gamma, const float* __restrict__ beta,
                          float* __restrict__ out, int N) {
    int i = blockIdx.x * 256 + threadIdx.x;
    if (i >= N * 16) return;
    int node = i >> 4, cc = i & 15;
    const short8* A8 = (const short8*)A;
    size_t srows = (size_t)(N + 1) * 2;
    short8 v = A8[(size_t)(cc >> 1) * srows + (size_t)node * 2 + (cc & 1)];
    float2 ms = stats[node];
    float4 o0, o1;
    o0.x = (bfs(v[0]) - ms.x) * ms.y * gamma[cc * 8 + 0] + beta[cc * 8 + 0];
    o0.y = (bfs(v[1]) - ms.x) * ms.y * gamma[cc * 8 + 1] + beta[cc * 8 + 1];
    o0.z = (bfs(v[2]) - ms.x) * ms.y * gamma[cc * 8 + 2] + beta[cc * 8 + 2];
    o0.w = (bfs(v[3]) - ms.x) * ms.y * gamma[cc * 8 + 3] + beta[cc * 8 + 3];
    o1.x = (bfs(v[4]) - ms.x) * ms.y * gamma[cc * 8 + 4] + beta[cc * 8 + 4];
    o1.y = (bfs(v[5]) - ms.x) * ms.y * gamma[cc * 8 + 5] + beta[cc * 8 + 5];
    o1.z = (bfs(v[6]) - ms.x) * ms.y * gamma[cc * 8 + 6] + beta[cc * 8 + 6];
    o1.w = (bfs(v[7]) - ms.x) * ms.y * gamma[cc * 8 + 7] + beta[cc * 8 + 7];
    ((float4*)out)[(size_t)node * 32 + cc * 2]     = o0;
    ((float4*)out)[(size_t)node * 32 + cc * 2 + 1] = o1;
}

// ---------------- launch ----------------
extern "C" void kernel_launch(void* const* d_in, const int* in_sizes, int n_in,
                              void* d_out, int out_size, void* d_ws, size_t ws_size,
                              hipStream_t stream) {
    const float* x  = (const float*)d_in[0];
    const int*   ei = (const int*)d_in[1];
    const float* W1 = (const float*)d_in[2];
    const float* b1 = (const float*)d_in[3];
    const float* W2 = (const float*)d_in[4];
    const float* b2 = (const float*)d_in[5];
    const float* g1 = (const float*)d_in[6];
    const float* be1 = (const float*)d_in[7];
    const float* g2 = (const float*)d_in[8];
    const float* be2 = (const float*)d_in[9];

    int N = in_sizes[0] / FDIM;
    int E = in_sizes[1] / 2;
    const int* srcp = ei;
    const int* dstp = ei + E;
    float* out = (float*)d_out;

    char* w = (char*)d_ws;
    size_t off = 0;
    auto take = [&](size_t bytes) {
        void* p = w + off;
        off = (off + bytes + 255) & ~(size_t)255;
        return p;
    };
    int nbk  = (N + 511) >> BSH;
    int nblk = (E + EPB - 1) / EPB;

    ushort* H   = (ushort*)take((size_t)(N + 1) * FDIM * sizeof(ushort)); // sliced h'
    ushort* A   = (ushort*)take((size_t)(N + 1) * FDIM * sizeof(ushort)); // sliced pre-LN acts
    // aliases inside A (both dead before A's first write in agg1):
    uint* ebuf  = (uint*)A;
    uint* mat   = (uint*)((char*)A + (((size_t)E * 4 + 255) & ~(size_t)255));
    ushort* WT1 = (ushort*)take(128 * 128 * sizeof(ushort));
    ushort* WT2 = (ushort*)take(128 * 128 * sizeof(ushort));
    uint* btot   = (uint*)take((size_t)nbk * sizeof(uint));
    uint* padtot = (uint*)take((size_t)nbk * sizeof(uint));
    int* deg     = (int*)take((size_t)N * sizeof(int));
    int* rowptr  = (int*)take((size_t)(N + 1) * sizeof(int));
    int* colb    = (int*)take((size_t)(E + 7 * (size_t)N + 1024) * sizeof(int));
    float* dinv  = (float*)take((size_t)N * sizeof(float));
    float2* stats = (float2*)take((size_t)N * sizeof(float2));
    float2* pstat = (float2*)d_out;          // scratch in d_out; dead before final write
    (void)ws_size;

    int ngemm = (N + 63) / 64;
    int naggb = 8 * ((N + 63) / 64);

    // weights -> W^T bf16 + zero H sentinel rows
    k_wt2<<<257, 128, 0, stream>>>(W1, W2, WT1, WT2, H, N);

    // bucketed CSR build (no global atomics)
    k_bcount<<<nblk, 256, 0, stream>>>(dstp, mat, nbk, E);
    k_colscan<<<nbk, 1024, 0, stream>>>(mat, btot, nbk, nblk);
    k_bscatter<<<nblk, 256, 0, stream>>>(srcp, dstp, mat, btot, ebuf, nbk, E);
    k_bdeg<<<nbk, 256, 0, stream>>>(ebuf, btot, deg, dinv, padtot, N, nbk);

    // MEGA: gemm1 (fp32 in) || D2 bucket fill
    k_mega<<<ngemm + nbk, 256, 0, stream>>>(x, WT1, dinv, H, N, ngemm,
                                            ebuf, btot, padtot, deg, rowptr, colb, nbk);

    // layer 1: sliced agg -> LN stats (LN applied inside gemm2 staging)
    k_agg_s<<<naggb, 256, 0, stream>>>(H, rowptr, colb, dinv, b1, A, pstat, N);
    k_lnstat<<<(N + 255) / 256, 256, 0, stream>>>(pstat, stats, N);

    // layer 2: gemm (sliced A + LN fused) -> sliced agg -> LN stats -> final apply
    k_gemm<1><<<ngemm, 256, 0, stream>>>(A, WT2, dinv, stats, g1, be1, H, N);
    k_agg_s<<<naggb, 256, 0, stream>>>(H, rowptr, colb, dinv, b2, A, pstat, N);
    k_lnstat<<<(N + 255) / 256, 256, 0, stream>>>(pstat, stats, N);
    k_lnapply<<<(N * 16 + 255) / 256, 256, 0, stream>>>(A, stats, g2, be2, out, N);
}

// Round 15
// 284.609 us; speedup vs baseline: 1.0035x; 1.0035x over previous
//
#include <hip/hip_runtime.h>

#define FDIM 128
#define LN_EPS 1e-5f
#define BSH 9              // 512 nodes per bucket
#define EPB 2048           // edges per block in bucket passes

typedef short short8 __attribute__((ext_vector_type(8)));
typedef float f32x4 __attribute__((ext_vector_type(4)));

__device__ __forceinline__ ushort f2bf(float f) {
    uint u = __float_as_uint(f);
    u += 0x7fff + ((u >> 16) & 1);      // RNE
    return (ushort)(u >> 16);
}
__device__ __forceinline__ float bflo(uint u) { return __uint_as_float(u << 16); }
__device__ __forceinline__ float bfhi(uint u) { return __uint_as_float(u & 0xffff0000u); }
__device__ __forceinline__ float bfs(short s) { return __uint_as_float(((uint)(ushort)s) << 16); }

// ---------------- bucketed CSR build (no global atomics) — proven R12 ----------------
__global__ __launch_bounds__(256) void k_bcount(const int* __restrict__ dst,
                                                uint* __restrict__ mat, int nbk, int E) {
    __shared__ uint cnt[512];
    int t = threadIdx.x;
    for (int i = t; i < nbk; i += 256) cnt[i] = 0;
    __syncthreads();
    int base = blockIdx.x * EPB, end = min(base + EPB, E);
    for (int e = base + t; e < end; e += 256)
        atomicAdd(&cnt[(uint)dst[e] >> BSH], 1u);
    __syncthreads();
    for (int i = t; i < nbk; i += 256) mat[(size_t)blockIdx.x * nbk + i] = cnt[i];
}

__global__ __launch_bounds__(1024) void k_colscan(uint* __restrict__ mat,
                                                  uint* __restrict__ btot, int nbk, int nblk) {
    __shared__ uint s[1024];
    int b = blockIdx.x, t = threadIdx.x;
    uint run = 0;
    for (int base = 0; base < nblk; base += 1024) {
        int i = base + t;
        uint v = (i < nblk) ? mat[(size_t)i * nbk + b] : 0;
        s[t] = v;
        __syncthreads();
        for (int off = 1; off < 1024; off <<= 1) {
            uint u = (t >= off) ? s[t - off] : 0;
            __syncthreads();
            s[t] += u;
            __syncthreads();
        }
        if (i < nblk) mat[(size_t)i * nbk + b] = run + s[t] - v;
        run += s[1023];
        __syncthreads();
    }
    if (t == 0) btot[b] = run;
}

__global__ __launch_bounds__(256) void k_bscatter(const int* __restrict__ src,
                                                  const int* __restrict__ dst,
                                                  const uint* __restrict__ mat,
                                                  const uint* __restrict__ btot,
                                                  uint* __restrict__ ebuf, int nbk, int E) {
    __shared__ uint cur[512];
    __shared__ uint ps[256];
    int t = threadIdx.x;
    uint v = (t < nbk) ? btot[t] : 0;
    ps[t] = v;
    __syncthreads();
    for (int off = 1; off < 256; off <<= 1) {
        uint u = (t >= off) ? ps[t - off] : 0;
        __syncthreads();
        ps[t] += u;
        __syncthreads();
    }
    if (t < nbk) cur[t] = (ps[t] - v) + mat[(size_t)blockIdx.x * nbk + t];
    __syncthreads();
    int base = blockIdx.x * EPB, end = min(base + EPB, E);
    for (int e = base + t; e < end; e += 256) {
        uint d = (uint)dst[e];
        uint off = atomicAdd(&cur[d >> BSH], 1u);
        ebuf[off] = ((d & 511u) << 17) | (uint)src[e];
    }
}

__global__ __launch_bounds__(256) void k_bdeg(const uint* __restrict__ ebuf,
                                              const uint* __restrict__ btot,
                                              int* __restrict__ deg, float* __restrict__ dinv,
                                              uint* __restrict__ padtot, int N, int nbk) {
    __shared__ uint cnt[512];
    __shared__ uint ps[256];
    __shared__ uint begs;
    int b = blockIdx.x, t = threadIdx.x;
    for (int i = t; i < 512; i += 256) cnt[i] = 0;
    uint v = (t < nbk) ? btot[t] : 0;
    ps[t] = v;
    __syncthreads();
    for (int off = 1; off < 256; off <<= 1) {
        uint u = (t >= off) ? ps[t - off] : 0;
        __syncthreads();
        ps[t] += u;
        __syncthreads();
    }
    if (t == b) begs = ps[t] - v;
    __syncthreads();
    uint beg = begs, cn = btot[b];
    for (uint i = t; i < cn; i += 256) atomicAdd(&cnt[ebuf[beg + i] >> 17], 1u);
    __syncthreads();
    int n0 = b << BSH;
    uint loc = 0;
    for (int i = t; i < 512; i += 256) {
        int n = n0 + i;
        if (n < N) {
            uint dg = cnt[i];
            deg[n] = (int)dg;
            dinv[n] = rsqrtf((float)dg + 1.0f);
            loc += (dg + 7u) & ~7u;
        }
    }
    ps[t] = loc;
    __syncthreads();
    for (int off = 128; off >= 1; off >>= 1) {
        if (t < off) ps[t] += ps[t + off];
        __syncthreads();
    }
    if (t == 0) padtot[b] = ps[0];
}

__device__ __forceinline__ void bfill_body(const uint* __restrict__ ebuf,
                                           const uint* __restrict__ btot,
                                           const uint* __restrict__ padtot,
                                           const int* __restrict__ deg,
                                           int* __restrict__ rowptr, int* __restrict__ col,
                                           int N, int nbk, int b) {
    __shared__ uint ps[256];
    __shared__ uint curf[512];
    __shared__ uint sc0, sc1;
    int t = threadIdx.x;
    uint v = (t < nbk) ? btot[t] : 0;
    ps[t] = v;
    __syncthreads();
    for (int off = 1; off < 256; off <<= 1) {
        uint u = (t >= off) ? ps[t - off] : 0;
        __syncthreads();
        ps[t] += u;
        __syncthreads();
    }
    if (t == b) sc0 = ps[t] - v;
    __syncthreads();
    uint w = (t < nbk) ? padtot[t] : 0;
    ps[t] = w;
    __syncthreads();
    for (int off = 1; off < 256; off <<= 1) {
        uint u = (t >= off) ? ps[t - off] : 0;
        __syncthreads();
        ps[t] += u;
        __syncthreads();
    }
    if (t == b) sc1 = ps[t] - w;
    if (b == nbk - 1 && t == nbk - 1) rowptr[N] = (int)ps[t];
    __syncthreads();
    uint beg = sc0, cn = btot[b], base = sc1;
    int n0 = b << BSH;
    int nA = n0 + 2 * t, nB = nA + 1;
    uint dA = (nA < N) ? (uint)deg[nA] : 0;
    uint dB = (nB < N) ? (uint)deg[nB] : 0;
    uint pA = (dA + 7u) & ~7u, pB = (dB + 7u) & ~7u;
    uint pair = pA + pB;
    ps[t] = pair;
    __syncthreads();
    for (int off = 1; off < 256; off <<= 1) {
        uint u = (t >= off) ? ps[t - off] : 0;
        __syncthreads();
        ps[t] += u;
        __syncthreads();
    }
    uint pex = ps[t] - pair;
    uint rA = base + pex, rB = rA + pA;
    curf[2 * t] = rA; curf[2 * t + 1] = rB;
    if (nA < N) rowptr[nA] = (int)rA;
    if (nB < N) rowptr[nB] = (int)rB;
    if (nA < N) for (uint k = dA; k < pA; ++k) col[rA + k] = N;
    if (nB < N) for (uint k = dB; k < pB; ++k) col[rB + k] = N;
    __syncthreads();
    for (uint i = t; i < cn; i += 256) {
        uint e = ebuf[beg + i];
        uint p = atomicAdd(&curf[e >> 17], 1u);
        col[p] = (int)(e & 0x1FFFFu);
    }
}

// -------- weights -> W^T bf16 + zero sentinel rows (row N of each H slice) --------
__global__ void k_wt2(const float* __restrict__ W1, const float* __restrict__ W2,
                      ushort* __restrict__ WT1, ushort* __restrict__ WT2,
                      ushort* __restrict__ H, int N) {
    int b = blockIdx.x, k = threadIdx.x;
    if (b < 128)      WT1[b * 128 + k] = f2bf(W1[k * 128 + b]);
    else if (b < 256) WT2[(b - 128) * 128 + k] = f2bf(W2[k * 128 + (b - 128)]);
    else if (k < 64) {                      // 8 slices x 16 ushorts = 64 uints
        int s = k >> 3, j = k & 7;
        ((uint*)(H + (size_t)s * (N + 1) * 16 + (size_t)N * 16))[j] = 0;
    }
}

// -------- GEMM: H'[slice][r][16] = dinv[r]*(X[r,:]@W), slice-major bf16 out --------
// MODE 0: X = fp32 rows.  MODE 1: X = sliced bf16 A + fused LayerNorm (stats,gamma,beta).
template <int MODE>
__device__ __forceinline__ void gemm_body(char* sXb, char* sWb,
                                          const void* __restrict__ Xin,
                                          const ushort* __restrict__ WT,
                                          const float* __restrict__ dinv,
                                          const float2* __restrict__ stats,
                                          const float* __restrict__ gamma,
                                          const float* __restrict__ beta,
                                          ushort* __restrict__ H, int N, int bid) {
    int t = threadIdx.x;
    int w = t >> 6, lane = t & 63;
    int cl = lane & 15, kq = lane >> 4;
    int base = bid * 64;

    const short8* Wg = (const short8*)WT;
#pragma unroll
    for (int k = 0; k < 8; ++k) {
        int idx = t + k * 256;
        int c = idx >> 4, ch = idx & 15;
        *(short8*)(sWb + c * 256 + ((ch * 16) ^ ((c & 7) << 4))) = Wg[idx];
    }

    if constexpr (MODE == 0) {
        const float4* X4 = (const float4*)Xin;
        size_t lim = (size_t)N * 32 - 1;
#pragma unroll
        for (int k = 0; k < 8; ++k) {
            int idx = t + k * 256;
            size_t gi = (size_t)base * 32 + idx;
            float4 v = X4[gi < lim ? gi : lim];
            ushort4 o;
            o.x = f2bf(v.x); o.y = f2bf(v.y); o.z = f2bf(v.z); o.w = f2bf(v.w);
            int row = idx >> 5, b8 = (idx & 31) * 8;
            *(ushort4*)(sXb + row * 256 + (b8 ^ ((row & 7) << 4))) = o;
        }
    } else {
        const short8* A8 = (const short8*)Xin;          // sliced: [slice][(N+1) rows][2 short8]
        size_t srows = (size_t)(N + 1) * 2;
#pragma unroll
        for (int k = 0; k < 4; ++k) {
            int idx = t + k * 256;                      // 64 rows x 16 chunks
            int row = idx >> 4, cc = idx & 15;
            int rc = min(base + row, N - 1);
            short8 v = A8[(size_t)(cc >> 1) * srows + (size_t)rc * 2 + (cc & 1)];
            float2 ms = stats[rc];
            short8 o;
#pragma unroll
            for (int j = 0; j < 8; ++j) {
                int f = cc * 8 + j;
                float val = (bfs(v[j]) - ms.x) * ms.y * gamma[f] + beta[f];
                o[j] = (short)f2bf(val);
            }
            *(short8*)(sXb + row * 256 + ((cc * 16) ^ ((row & 7) << 4))) = o;
        }
    }
    __syncthreads();

    int rl = w * 16 + cl;
    short8 b0, b1, b2, b3;
#pragma unroll
    for (int kt = 0; kt < 4; ++kt) {
        short8 v = *(const short8*)(sXb + rl * 256 + ((kt * 64 + kq * 16) ^ ((rl & 7) << 4)));
        if (kt == 0) b0 = v; else if (kt == 1) b1 = v; else if (kt == 2) b2 = v; else b3 = v;
    }

    int r = base + rl;
    bool ok = r < N;
    float di = dinv[min(r, N - 1)];
#pragma unroll
    for (int nt = 0; nt < 8; ++nt) {
        int c = nt * 16 + cl;
        int sw = (c & 7) << 4;
        f32x4 acc = {0.f, 0.f, 0.f, 0.f};
        acc = __builtin_amdgcn_mfma_f32_16x16x32_bf16(
            *(const short8*)(sWb + c * 256 + ((0 * 64 + kq * 16) ^ sw)), b0, acc, 0, 0, 0);
        acc = __builtin_amdgcn_mfma_f32_16x16x32_bf16(
            *(const short8*)(sWb + c * 256 + ((1 * 64 + kq * 16) ^ sw)), b1, acc, 0, 0, 0);
        acc = __builtin_amdgcn_mfma_f32_16x16x32_bf16(
            *(const short8*)(sWb + c * 256 + ((2 * 64 + kq * 16) ^ sw)), b2, acc, 0, 0, 0);
        acc = __builtin_amdgcn_mfma_f32_16x16x32_bf16(
            *(const short8*)(sWb + c * 256 + ((3 * 64 + kq * 16) ^ sw)), b3, acc, 0, 0, 0);
        if (ok) {
            ushort4 o;
            o.x = f2bf(acc[0] * di); o.y = f2bf(acc[1] * di);
            o.z = f2bf(acc[2] * di); o.w = f2bf(acc[3] * di);
            // slice-major: slice nt covers features nt*16..+15
            *(ushort4*)(H + (size_t)nt * (N + 1) * 16 + (size_t)r * 16 + kq * 4) = o;
        }
    }
}

template <int MODE>
__global__ __launch_bounds__(256) void k_gemm(const void* __restrict__ Xin,
                                              const ushort* __restrict__ WT,
                                              const float* __restrict__ dinv,
                                              const float2* __restrict__ stats,
                                              const float* __restrict__ gamma,
                                              const float* __restrict__ beta,
                                              ushort* __restrict__ H, int N) {
    __shared__ ushort sX[64 * 128];
    __shared__ ushort sW[128 * 128];
    gemm_body<MODE>((char*)sX, (char*)sW, Xin, WT, dinv, stats, gamma, beta, H, N, blockIdx.x);
}

// -------- MEGA: blocks [0,ngemm) = gemm1 (fp32 in), blocks [ngemm,ngemm+nbk) = D2 fill --------
__global__ __launch_bounds__(256) void k_mega(const void* __restrict__ Xin,
                                              const ushort* __restrict__ WT,
                                              const float* __restrict__ dinv,
                                              ushort* __restrict__ H, int N, int ngemm,
                                              const uint* __restrict__ ebuf,
                                              const uint* __restrict__ btot,
                                              const uint* __restrict__ padtot,
                                              const int* __restrict__ deg,
                                              int* __restrict__ rowptr,
                                              int* __restrict__ col, int nbk) {
    __shared__ ushort sX[64 * 128];
    __shared__ ushort sW[128 * 128];
    if (blockIdx.x < (uint)ngemm) {
        gemm_body<0>((char*)sX, (char*)sW, Xin, WT, dinv, nullptr, nullptr, nullptr, H, N, blockIdx.x);
    } else {
        bfill_body(ebuf, btot, padtot, deg, rowptr, col, N, nbk, blockIdx.x - ngemm);
    }
}

// ------- sliced aggregate: slice = blockIdx&7 (round-robin XCD alignment), -------
// 4 lanes/node (uint2 = 4 features), bias+ReLU, write sliced A + LN partial sums.
__global__ __launch_bounds__(256) void k_agg_s(const ushort* __restrict__ Hs,
                                               const int* __restrict__ rowptr,
                                               const int* __restrict__ col,
                                               const float* __restrict__ dinv,
                                               const float* __restrict__ bias,
                                               ushort* __restrict__ Aout,
                                               float2* __restrict__ pstat, int N) {
    int s = blockIdx.x & 7;
    int chunk = blockIdx.x >> 3;
    int w = threadIdx.x >> 6, lane = threadIdx.x & 63;
    int g = lane >> 2, fl = lane & 3;       // group of 4 lanes per node
    int node = chunk * 64 + w * 16 + g;
    bool valid = node < N;
    int nodec = valid ? node : N - 1;

    const uint2* Hu = (const uint2*)(Hs + (size_t)s * (N + 1) * 16);   // row = 4 uint2
    float di = dinv[nodec];
    uint2 hv = Hu[(size_t)nodec * 4 + fl];
    float a0 = bflo(hv.x), a1 = bfhi(hv.x), a2 = bflo(hv.y), a3 = bfhi(hv.y);

    int beg = rowptr[nodec];
    int deg8 = rowptr[nodec + 1] - beg;     // multiple of 8
    const int* cp = col + beg;

    for (int i = 0; i < deg8; i += 8) {
        int e0 = cp[i + 0], e1 = cp[i + 1], e2 = cp[i + 2], e3 = cp[i + 3];
        int e4 = cp[i + 4], e5 = cp[i + 5], e6 = cp[i + 6], e7 = cp[i + 7];
        uint2 u0 = Hu[(size_t)e0 * 4 + fl];
        uint2 u1 = Hu[(size_t)e1 * 4 + fl];
        uint2 u2 = Hu[(size_t)e2 * 4 + fl];
        uint2 u3 = Hu[(size_t)e3 * 4 + fl];
        uint2 u4 = Hu[(size_t)e4 * 4 + fl];
        uint2 u5 = Hu[(size_t)e5 * 4 + fl];
        uint2 u6 = Hu[(size_t)e6 * 4 + fl];
        uint2 u7 = Hu[(size_t)e7 * 4 + fl];
        a0 += bflo(u0.x); a1 += bfhi(u0.x); a2 += bflo(u0.y); a3 += bfhi(u0.y);
        a0 += bflo(u1.x); a1 += bfhi(u1.x); a2 += bflo(u1.y); a3 += bfhi(u1.y);
        a0 += bflo(u2.x); a1 += bfhi(u2.x); a2 += bflo(u2.y); a3 += bfhi(u2.y);
        a0 += bflo(u3.x); a1 += bfhi(u3.x); a2 += bflo(u3.y); a3 += bfhi(u3.y);
        a0 += bflo(u4.x); a1 += bfhi(u4.x); a2 += bflo(u4.y); a3 += bfhi(u4.y);
        a0 += bflo(u5.x); a1 += bfhi(u5.x); a2 += bflo(u5.y); a3 += bfhi(u5.y);
        a0 += bflo(u6.x); a1 += bfhi(u6.x); a2 += bflo(u6.y); a3 += bfhi(u6.y);
        a0 += bflo(u7.x); a1 += bfhi(u7.x); a2 += bflo(u7.y); a3 += bfhi(u7.y);
    }

    float4 bb = ((const float4*)bias)[s * 4 + fl];     // features s*16 + fl*4 ..+3
    a0 = fmaxf(fmaf(a0, di, bb.x), 0.f);
    a1 = fmaxf(fmaf(a1, di, bb.y), 0.f);
    a2 = fmaxf(fmaf(a2, di, bb.z), 0.f);
    a3 = fmaxf(fmaf(a3, di, bb.w), 0.f);

    float s1 = (a0 + a1) + (a2 + a3);
    float s2 = (a0 * a0 + a1 * a1) + (a2 * a2 + a3 * a3);
    s1 += __shfl_xor(s1, 1); s1 += __shfl_xor(s1, 2);  // 4-lane group reduce
    s2 += __shfl_xor(s2, 1); s2 += __shfl_xor(s2, 2);

    if (!valid) return;
    uint2 o;
    o.x = (uint)f2bf(a0) | ((uint)f2bf(a1) << 16);
    o.y = (uint)f2bf(a2) | ((uint)f2bf(a3) << 16);
    ((uint2*)(Aout + (size_t)s * (N + 1) * 16))[(size_t)node * 4 + fl] = o;
    if (fl == 0) pstat[(size_t)node * 8 + s] = make_float2(s1, s2);
}

// per-node LN stats from 8 slice partials
__global__ void k_lnstat(const float2* __restrict__ pstat, float2* __restrict__ stats, int N) {
    int i = blockIdx.x * 256 + threadIdx.x;
    if (i < N) {
        float s1 = 0.f, s2 = 0.f;
#pragma unroll
        for (int s = 0; s < 8; ++s) {
            float2 p = pstat[(size_t)i * 8 + s];
            s1 += p.x; s2 += p.y;
        }
        float mu = s1 * (1.f / 128.f);
        float var = s2 * (1.f / 128.f) - mu * mu;
        stats[i] = make_float2(mu, rsqrtf(var + LN_EPS));
    }
}

// final LN apply: sliced bf16 A2 -> fp32 [node][128]
__global__ void k_lnapply(const ushort* __restrict__ A, const float2* __restrict__ stats,
                          const float* __restrict__ gamma, const float* __restrict__ beta,
                          float* __restrict__ out, int N) {
    int i = blockIdx.x * 256 + threadIdx.x;
    if (i >= N * 16) return;
    int node = i >> 4, cc = i & 15;
    const short8* A8 = (const short8*)A;
    size_t srows = (size_t)(N + 1) * 2;
    short8 v = A8[(size_t)(cc >> 1) * srows + (size_t)node * 2 + (cc & 1)];
    float2 ms = stats[node];
    float4 o0, o1;
    o0.x = (bfs(v[0]) - ms.x) * ms.y * gamma[cc * 8 + 0] + beta[cc * 8 + 0];
    o0.y = (bfs(v[1]) - ms.x) * ms.y * gamma[cc * 8 + 1] + beta[cc * 8 + 1];
    o0.z = (bfs(v[2]) - ms.x) * ms.y * gamma[cc * 8 + 2] + beta[cc * 8 + 2];
    o0.w = (bfs(v[3]) - ms.x) * ms.y * gamma[cc * 8 + 3] + beta[cc * 8 + 3];
    o1.x = (bfs(v[4]) - ms.x) * ms.y * gamma[cc * 8 + 4] + beta[cc * 8 + 4];
    o1.y = (bfs(v[5]) - ms.x) * ms.y * gamma[cc * 8 + 5] + beta[cc * 8 + 5];
    o1.z = (bfs(v[6]) - ms.x) * ms.y * gamma[cc * 8 + 6] + beta[cc * 8 + 6];
    o1.w = (bfs(v[7]) - ms.x) * ms.y * gamma[cc * 8 + 7] + beta[cc * 8 + 7];
    ((float4*)out)[(size_t)node * 32 + cc * 2]     = o0;
    ((float4*)out)[(size_t)node * 32 + cc * 2 + 1] = o1;
}

// ---------------- launch ----------------
extern "C" void kernel_launch(void* const* d_in, const int* in_sizes, int n_in,
                              void* d_out, int out_size, void* d_ws, size_t ws_size,
                              hipStream_t stream) {
    const float* x  = (const float*)d_in[0];
    const int*   ei = (const int*)d_in[1];
    const float* W1 = (const float*)d_in[2];
    const float* b1 = (const float*)d_in[3];
    const float* W2 = (const float*)d_in[4];
    const float* b2 = (const float*)d_in[5];
    const float* g1 = (const float*)d_in[6];
    const float* be1 = (const float*)d_in[7];
    const float* g2 = (const float*)d_in[8];
    const float* be2 = (const float*)d_in[9];

    int N = in_sizes[0] / FDIM;
    int E = in_sizes[1] / 2;
    const int* srcp = ei;
    const int* dstp = ei + E;
    float* out = (float*)d_out;

    char* w = (char*)d_ws;
    size_t off = 0;
    auto take = [&](size_t bytes) {
        void* p = w + off;
        off = (off + bytes + 255) & ~(size_t)255;
        return p;
    };
    int nbk  = (N + 511) >> BSH;
    int nblk = (E + EPB - 1) / EPB;

    ushort* H   = (ushort*)take((size_t)(N + 1) * FDIM * sizeof(ushort)); // sliced h'
    ushort* A   = (ushort*)take((size_t)(N + 1) * FDIM * sizeof(ushort)); // sliced pre-LN acts
    // aliases inside A (both dead before A's first write in agg1):
    uint* ebuf  = (uint*)A;
    uint* mat   = (uint*)((char*)A + (((size_t)E * 4 + 255) & ~(size_t)255));
    ushort* WT1 = (ushort*)take(128 * 128 * sizeof(ushort));
    ushort* WT2 = (ushort*)take(128 * 128 * sizeof(ushort));
    uint* btot   = (uint*)take((size_t)nbk * sizeof(uint));
    uint* padtot = (uint*)take((size_t)nbk * sizeof(uint));
    int* deg     = (int*)take((size_t)N * sizeof(int));
    int* rowptr  = (int*)take((size_t)(N + 1) * sizeof(int));
    int* colb    = (int*)take((size_t)(E + 7 * (size_t)N + 1024) * sizeof(int));
    float* dinv  = (float*)take((size_t)N * sizeof(float));
    float2* stats = (float2*)take((size_t)N * sizeof(float2));
    float2* pstat = (float2*)d_out;          // scratch in d_out; dead before final write
    (void)ws_size;

    int ngemm = (N + 63) / 64;
    int naggb = 8 * ((N + 63) / 64);

    // weights -> W^T bf16 + zero H sentinel rows
    k_wt2<<<257, 128, 0, stream>>>(W1, W2, WT1, WT2, H, N);

    // bucketed CSR build (no global atomics)
    k_bcount<<<nblk, 256, 0, stream>>>(dstp, mat, nbk, E);
    k_colscan<<<nbk, 1024, 0, stream>>>(mat, btot, nbk, nblk);
    k_bscatter<<<nblk, 256, 0, stream>>>(srcp, dstp, mat, btot, ebuf, nbk, E);
    k_bdeg<<<nbk, 256, 0, stream>>>(ebuf, btot, deg, dinv, padtot, N, nbk);

    // MEGA: gemm1 (fp32 in) || D2 bucket fill
    k_mega<<<ngemm + nbk, 256, 0, stream>>>(x, WT1, dinv, H, N, ngemm,
                                            ebuf, btot, padtot, deg, rowptr, colb, nbk);

    // layer 1: sliced agg -> LN stats (LN applied inside gemm2 staging)
    k_agg_s<<<naggb, 256, 0, stream>>>(H, rowptr, colb, dinv, b1, A, pstat, N);
    k_lnstat<<<(N + 255) / 256, 256, 0, stream>>>(pstat, stats, N);

    // layer 2: gemm (sliced A + LN fused) -> sliced agg -> LN stats -> final apply
    k_gemm<1><<<ngemm, 256, 0, stream>>>(A, WT2, dinv, stats, g1, be1, H, N);
    k_agg_s<<<naggb, 256, 0, stream>>>(H, rowptr, colb, dinv, b2, A, pstat, N);
    k_lnstat<<<(N + 255) / 256, 256, 0, stream>>>(pstat, stats, N);
    k_lnapply<<<(N * 16 + 255) / 256, 256, 0, stream>>>(A, stats, g2, be2, out, N);
}

// Round 16
// 223.507 us; speedup vs baseline: 1.2778x; 1.2734x over previous
//
#include <hip/hip_runtime.h>

#define FDIM 128
#define LN_EPS 1e-5f
#define BSH 9              // 512 nodes per bucket
#define EPB 2048           // edges per block in bucket passes

typedef short short8 __attribute__((ext_vector_type(8)));
typedef float f32x4 __attribute__((ext_vector_type(4)));

__device__ __forceinline__ ushort f2bf(float f) {
    uint u = __float_as_uint(f);
    u += 0x7fff + ((u >> 16) & 1);      // RNE
    return (ushort)(u >> 16);
}
__device__ __forceinline__ float bflo(uint u) { return __uint_as_float(u << 16); }
__device__ __forceinline__ float bfhi(uint u) { return __uint_as_float(u & 0xffff0000u); }

// ---------------- bucketed CSR build (no global atomics) — proven R12, pad-16 ----------------
__global__ __launch_bounds__(256) void k_bcount(const int* __restrict__ dst,
                                                uint* __restrict__ mat, int nbk, int E) {
    __shared__ uint cnt[512];
    int t = threadIdx.x;
    for (int i = t; i < nbk; i += 256) cnt[i] = 0;
    __syncthreads();
    int base = blockIdx.x * EPB, end = min(base + EPB, E);
    for (int e = base + t; e < end; e += 256)
        atomicAdd(&cnt[(uint)dst[e] >> BSH], 1u);
    __syncthreads();
    for (int i = t; i < nbk; i += 256) mat[(size_t)blockIdx.x * nbk + i] = cnt[i];
}

__global__ __launch_bounds__(1024) void k_colscan(uint* __restrict__ mat,
                                                  uint* __restrict__ btot, int nbk, int nblk) {
    __shared__ uint s[1024];
    int b = blockIdx.x, t = threadIdx.x;
    uint run = 0;
    for (int base = 0; base < nblk; base += 1024) {
        int i = base + t;
        uint v = (i < nblk) ? mat[(size_t)i * nbk + b] : 0;
        s[t] = v;
        __syncthreads();
        for (int off = 1; off < 1024; off <<= 1) {
            uint u = (t >= off) ? s[t - off] : 0;
            __syncthreads();
            s[t] += u;
            __syncthreads();
        }
        if (i < nblk) mat[(size_t)i * nbk + b] = run + s[t] - v;
        run += s[1023];
        __syncthreads();
    }
    if (t == 0) btot[b] = run;
}

__global__ __launch_bounds__(256) void k_bscatter(const int* __restrict__ src,
                                                  const int* __restrict__ dst,
                                                  const uint* __restrict__ mat,
                                                  const uint* __restrict__ btot,
                                                  uint* __restrict__ ebuf, int nbk, int E) {
    __shared__ uint cur[512];
    __shared__ uint ps[256];
    int t = threadIdx.x;
    uint v = (t < nbk) ? btot[t] : 0;
    ps[t] = v;
    __syncthreads();
    for (int off = 1; off < 256; off <<= 1) {
        uint u = (t >= off) ? ps[t - off] : 0;
        __syncthreads();
        ps[t] += u;
        __syncthreads();
    }
    if (t < nbk) cur[t] = (ps[t] - v) + mat[(size_t)blockIdx.x * nbk + t];
    __syncthreads();
    int base = blockIdx.x * EPB, end = min(base + EPB, E);
    for (int e = base + t; e < end; e += 256) {
        uint d = (uint)dst[e];
        uint off = atomicAdd(&cur[d >> BSH], 1u);
        ebuf[off] = ((d & 511u) << 17) | (uint)src[e];
    }
}

__global__ __launch_bounds__(256) void k_bdeg(const uint* __restrict__ ebuf,
                                              const uint* __restrict__ btot,
                                              int* __restrict__ deg, float* __restrict__ dinv,
                                              uint* __restrict__ padtot, int N, int nbk) {
    __shared__ uint cnt[512];
    __shared__ uint ps[256];
    __shared__ uint begs;
    int b = blockIdx.x, t = threadIdx.x;
    for (int i = t; i < 512; i += 256) cnt[i] = 0;
    uint v = (t < nbk) ? btot[t] : 0;
    ps[t] = v;
    __syncthreads();
    for (int off = 1; off < 256; off <<= 1) {
        uint u = (t >= off) ? ps[t - off] : 0;
        __syncthreads();
        ps[t] += u;
        __syncthreads();
    }
    if (t == b) begs = ps[t] - v;
    __syncthreads();
    uint beg = begs, cn = btot[b];
    for (uint i = t; i < cn; i += 256) atomicAdd(&cnt[ebuf[beg + i] >> 17], 1u);
    __syncthreads();
    int n0 = b << BSH;
    uint loc = 0;
    for (int i = t; i < 512; i += 256) {
        int n = n0 + i;
        if (n < N) {
            uint dg = cnt[i];
            deg[n] = (int)dg;
            dinv[n] = rsqrtf((float)dg + 1.0f);
            loc += (dg + 15u) & ~15u;        // pad-16
        }
    }
    ps[t] = loc;
    __syncthreads();
    for (int off = 128; off >= 1; off >>= 1) {
        if (t < off) ps[t] += ps[t + off];
        __syncthreads();
    }
    if (t == 0) padtot[b] = ps[0];
}

__device__ __forceinline__ void bfill_body(const uint* __restrict__ ebuf,
                                           const uint* __restrict__ btot,
                                           const uint* __restrict__ padtot,
                                           const int* __restrict__ deg,
                                           int* __restrict__ rowptr, int* __restrict__ col,
                                           int N, int nbk, int b) {
    __shared__ uint ps[256];
    __shared__ uint curf[512];
    __shared__ uint sc0, sc1;
    int t = threadIdx.x;
    uint v = (t < nbk) ? btot[t] : 0;
    ps[t] = v;
    __syncthreads();
    for (int off = 1; off < 256; off <<= 1) {
        uint u = (t >= off) ? ps[t - off] : 0;
        __syncthreads();
        ps[t] += u;
        __syncthreads();
    }
    if (t == b) sc0 = ps[t] - v;
    __syncthreads();
    uint w = (t < nbk) ? padtot[t] : 0;
    ps[t] = w;
    __syncthreads();
    for (int off = 1; off < 256; off <<= 1) {
        uint u = (t >= off) ? ps[t - off] : 0;
        __syncthreads();
        ps[t] += u;
        __syncthreads();
    }
    if (t == b) sc1 = ps[t] - w;
    if (b == nbk - 1 && t == nbk - 1) rowptr[N] = (int)ps[t];
    __syncthreads();
    uint beg = sc0, cn = btot[b], base = sc1;
    int n0 = b << BSH;
    int nA = n0 + 2 * t, nB = nA + 1;
    uint dA = (nA < N) ? (uint)deg[nA] : 0;
    uint dB = (nB < N) ? (uint)deg[nB] : 0;
    uint pA = (dA + 15u) & ~15u, pB = (dB + 15u) & ~15u;   // pad-16
    uint pair = pA + pB;
    ps[t] = pair;
    __syncthreads();
    for (int off = 1; off < 256; off <<= 1) {
        uint u = (t >= off) ? ps[t - off] : 0;
        __syncthreads();
        ps[t] += u;
        __syncthreads();
    }
    uint pex = ps[t] - pair;
    uint rA = base + pex, rB = rA + pA;
    curf[2 * t] = rA; curf[2 * t + 1] = rB;
    if (nA < N) rowptr[nA] = (int)rA;
    if (nB < N) rowptr[nB] = (int)rB;
    if (nA < N) for (uint k = dA; k < pA; ++k) col[rA + k] = N;   // zero-row sentinels
    if (nB < N) for (uint k = dB; k < pB; ++k) col[rB + k] = N;
    __syncthreads();
    for (uint i = t; i < cn; i += 256) {
        uint e = ebuf[beg + i];
        uint p = atomicAdd(&curf[e >> 17], 1u);
        col[p] = (int)(e & 0x1FFFFu);
    }
}

// ---------------- W[128,128] fp32 -> W^T bf16 (both weights, one launch) ----------------
__global__ void k_wt2(const float* __restrict__ W1, const float* __restrict__ W2,
                      ushort* __restrict__ WT1, ushort* __restrict__ WT2) {
    int b = blockIdx.x, k = threadIdx.x;
    if (b < 128) WT1[b * 128 + k] = f2bf(W1[k * 128 + b]);
    else         WT2[(b - 128) * 128 + k] = f2bf(W2[k * 128 + (b - 128)]);
}

// -------- GEMM body: H'[r] = dinv[r] * (X[r,:] @ W)  (bf16 out, pre-scaled) --------
template <bool F32IN>
__device__ __forceinline__ void gemm_body(char* sXb, char* sWb,
                                          const void* __restrict__ Xin,
                                          const ushort* __restrict__ WT,
                                          const float* __restrict__ dinv,
                                          ushort* __restrict__ H, int N, int bid) {
    int t = threadIdx.x;
    int w = t >> 6, lane = t & 63;
    int cl = lane & 15, kq = lane >> 4;
    int base = bid * 64;

    const short8* Wg = (const short8*)WT;
#pragma unroll
    for (int k = 0; k < 8; ++k) {
        int idx = t + k * 256;
        int c = idx >> 4, ch = idx & 15;
        *(short8*)(sWb + c * 256 + ((ch * 16) ^ ((c & 7) << 4))) = Wg[idx];
    }

    if constexpr (F32IN) {
        const float4* X4 = (const float4*)Xin;
        size_t lim = (size_t)N * 32 - 1;
#pragma unroll
        for (int k = 0; k < 8; ++k) {
            int idx = t + k * 256;
            size_t gi = (size_t)base * 32 + idx;
            float4 v = X4[gi < lim ? gi : lim];
            ushort4 o;
            o.x = f2bf(v.x); o.y = f2bf(v.y); o.z = f2bf(v.z); o.w = f2bf(v.w);
            int row = idx >> 5, b8 = (idx & 31) * 8;
            *(ushort4*)(sXb + row * 256 + (b8 ^ ((row & 7) << 4))) = o;
        }
    } else {
        const short8* X8 = (const short8*)Xin;
        size_t lim = (size_t)N * 16 - 1;
#pragma unroll
        for (int k = 0; k < 4; ++k) {
            int idx = t + k * 256;
            size_t gi = (size_t)base * 16 + idx;
            short8 v = X8[gi < lim ? gi : lim];
            int row = idx >> 4, b16 = (idx & 15) * 16;
            *(short8*)(sXb + row * 256 + (b16 ^ ((row & 7) << 4))) = v;
        }
    }
    __syncthreads();

    int rl = w * 16 + cl;
    short8 b0, b1, b2, b3;
#pragma unroll
    for (int kt = 0; kt < 4; ++kt) {
        short8 v = *(const short8*)(sXb + rl * 256 + ((kt * 64 + kq * 16) ^ ((rl & 7) << 4)));
        if (kt == 0) b0 = v; else if (kt == 1) b1 = v; else if (kt == 2) b2 = v; else b3 = v;
    }

    int r = base + rl;
    bool ok = r < N;
    float di = dinv[min(r, N - 1)];
#pragma unroll
    for (int nt = 0; nt < 8; ++nt) {
        int c = nt * 16 + cl;
        int sw = (c & 7) << 4;
        f32x4 acc = {0.f, 0.f, 0.f, 0.f};
        acc = __builtin_amdgcn_mfma_f32_16x16x32_bf16(
            *(const short8*)(sWb + c * 256 + ((0 * 64 + kq * 16) ^ sw)), b0, acc, 0, 0, 0);
        acc = __builtin_amdgcn_mfma_f32_16x16x32_bf16(
            *(const short8*)(sWb + c * 256 + ((1 * 64 + kq * 16) ^ sw)), b1, acc, 0, 0, 0);
        acc = __builtin_amdgcn_mfma_f32_16x16x32_bf16(
            *(const short8*)(sWb + c * 256 + ((2 * 64 + kq * 16) ^ sw)), b2, acc, 0, 0, 0);
        acc = __builtin_amdgcn_mfma_f32_16x16x32_bf16(
            *(const short8*)(sWb + c * 256 + ((3 * 64 + kq * 16) ^ sw)), b3, acc, 0, 0, 0);
        if (ok) {
            ushort4 o;
            o.x = f2bf(acc[0] * di); o.y = f2bf(acc[1] * di);
            o.z = f2bf(acc[2] * di); o.w = f2bf(acc[3] * di);
            *(ushort4*)(H + (size_t)r * 128 + nt * 16 + kq * 4) = o;
        }
    }
}

template <bool F32IN>
__global__ __launch_bounds__(256) void k_gemm(const void* __restrict__ Xin,
                                              const ushort* __restrict__ WT,
                                              const float* __restrict__ dinv,
                                              ushort* __restrict__ H, int N) {
    __shared__ ushort sX[64 * 128];
    __shared__ ushort sW[128 * 128];
    gemm_body<F32IN>((char*)sX, (char*)sW, Xin, WT, dinv, H, N, blockIdx.x);
}

// -------- MEGA: blocks [0,ngemm) = gemm1 (fp32 in), blocks [ngemm,ngemm+nbk) = D2 fill --------
__global__ __launch_bounds__(256) void k_mega(const void* __restrict__ Xin,
                                              const ushort* __restrict__ WT,
                                              const float* __restrict__ dinv,
                                              ushort* __restrict__ H, int N, int ngemm,
                                              const uint* __restrict__ ebuf,
                                              const uint* __restrict__ btot,
                                              const uint* __restrict__ padtot,
                                              const int* __restrict__ deg,
                                              int* __restrict__ rowptr,
                                              int* __restrict__ col, int nbk) {
    __shared__ ushort sX[64 * 128];
    __shared__ ushort sW[128 * 128];
    if (blockIdx.x < (uint)ngemm) {
        gemm_body<true>((char*)sX, (char*)sW, Xin, WT, dinv, H, N, blockIdx.x);
    } else {
        bfill_body(ebuf, btot, padtot, deg, rowptr, col, N, nbk, blockIdx.x - ngemm);
    }
}

// ------- aggregate(pre-scaled bf16 h') + bias + ReLU + LN -------
// 4 nodes/wave (16 lanes each, uint4 = 8 features/lane), pad-16 rows,
// 16 gathers in flight (deepened MLP); quarters exec-diverge on own deg16.
__global__ __launch_bounds__(256) void k_agg(const uint4* __restrict__ H4,  // (N+1) rows x 16 uint4
                                             const int* __restrict__ rowptr, // rounded-16
                                             const int* __restrict__ col,
                                             const float* __restrict__ dinv,
                                             const float* __restrict__ bias,
                                             const float* __restrict__ gamma,
                                             const float* __restrict__ beta,
                                             float* __restrict__ outf,
                                             uint4* __restrict__ outb,
                                             int N) {
    int wave = threadIdx.x >> 6;
    int lane = threadIdx.x & 63;
    int q = lane >> 4;
    int l = lane & 15;
    int node = blockIdx.x * 16 + wave * 4 + q;
    bool valid = node < N;
    int nodec = valid ? node : N - 1;

    float di = dinv[nodec];
    uint4 hs = H4[(uint)nodec * 16u + (uint)l];
    float a0 = bflo(hs.x), a1 = bfhi(hs.x), a2 = bflo(hs.y), a3 = bfhi(hs.y);
    float a4 = bflo(hs.z), a5 = bfhi(hs.z), a6 = bflo(hs.w), a7 = bfhi(hs.w);

    int beg = rowptr[nodec];
    int deg16 = rowptr[nodec + 1] - beg;    // multiple of 16, own count
    const int* cp = col + beg;              // 64B-aligned (all pads multiple of 16)

#define ACC(u)                                                             \
    a0 += bflo((u).x); a1 += bfhi((u).x); a2 += bflo((u).y); a3 += bfhi((u).y); \
    a4 += bflo((u).z); a5 += bfhi((u).z); a6 += bflo((u).w); a7 += bfhi((u).w);

    for (int i = 0; i < deg16; i += 16) {
        int4 c0 = *(const int4*)(cp + i);
        int4 c1 = *(const int4*)(cp + i + 4);
        int4 c2 = *(const int4*)(cp + i + 8);
        int4 c3 = *(const int4*)(cp + i + 12);
        uint4 u0 = H4[(uint)c0.x * 16u + (uint)l];
        uint4 u1 = H4[(uint)c0.y * 16u + (uint)l];
        uint4 u2 = H4[(uint)c0.z * 16u + (uint)l];
        uint4 u3 = H4[(uint)c0.w * 16u + (uint)l];
        uint4 u4 = H4[(uint)c1.x * 16u + (uint)l];
        uint4 u5 = H4[(uint)c1.y * 16u + (uint)l];
        uint4 u6 = H4[(uint)c1.z * 16u + (uint)l];
        uint4 u7 = H4[(uint)c1.w * 16u + (uint)l];
        uint4 u8 = H4[(uint)c2.x * 16u + (uint)l];
        uint4 u9 = H4[(uint)c2.y * 16u + (uint)l];
        uint4 ua = H4[(uint)c2.z * 16u + (uint)l];
        uint4 ub = H4[(uint)c2.w * 16u + (uint)l];
        uint4 uc = H4[(uint)c3.x * 16u + (uint)l];
        uint4 ud = H4[(uint)c3.y * 16u + (uint)l];
        uint4 ue = H4[(uint)c3.z * 16u + (uint)l];
        uint4 uf = H4[(uint)c3.w * 16u + (uint)l];
        ACC(u0) ACC(u1) ACC(u2) ACC(u3) ACC(u4) ACC(u5) ACC(u6) ACC(u7)
        ACC(u8) ACC(u9) ACC(ua) ACC(ub) ACC(uc) ACC(ud) ACC(ue) ACC(uf)
    }
#undef ACC

    float4 bb0 = ((const float4*)bias)[2 * l];
    float4 bb1 = ((const float4*)bias)[2 * l + 1];
    a0 = fmaxf(fmaf(a0, di, bb0.x), 0.f);
    a1 = fmaxf(fmaf(a1, di, bb0.y), 0.f);
    a2 = fmaxf(fmaf(a2, di, bb0.z), 0.f);
    a3 = fmaxf(fmaf(a3, di, bb0.w), 0.f);
    a4 = fmaxf(fmaf(a4, di, bb1.x), 0.f);
    a5 = fmaxf(fmaf(a5, di, bb1.y), 0.f);
    a6 = fmaxf(fmaf(a6, di, bb1.z), 0.f);
    a7 = fmaxf(fmaf(a7, di, bb1.w), 0.f);

    float s1 = ((a0 + a1) + (a2 + a3)) + ((a4 + a5) + (a6 + a7));
    float s2 = ((a0 * a0 + a1 * a1) + (a2 * a2 + a3 * a3)) +
               ((a4 * a4 + a5 * a5) + (a6 * a6 + a7 * a7));
#pragma unroll
    for (int off = 8; off >= 1; off >>= 1) {
        s1 += __shfl_xor(s1, off);
        s2 += __shfl_xor(s2, off);
    }
    float mu = s1 * (1.f / 128.f);
    float var = s2 * (1.f / 128.f) - mu * mu;
    float rs = rsqrtf(var + LN_EPS);

    float4 g0 = ((const float4*)gamma)[2 * l];
    float4 g1 = ((const float4*)gamma)[2 * l + 1];
    float4 e0 = ((const float4*)beta)[2 * l];
    float4 e1 = ((const float4*)beta)[2 * l + 1];
    float o0 = (a0 - mu) * rs * g0.x + e0.x;
    float o1 = (a1 - mu) * rs * g0.y + e0.y;
    float o2 = (a2 - mu) * rs * g0.z + e0.z;
    float o3 = (a3 - mu) * rs * g0.w + e0.w;
    float o4 = (a4 - mu) * rs * g1.x + e1.x;
    float o5 = (a5 - mu) * rs * g1.y + e1.y;
    float o6 = (a6 - mu) * rs * g1.z + e1.z;
    float o7 = (a7 - mu) * rs * g1.w + e1.w;

    if (!valid) return;
    if (outf) {
        ((float4*)outf)[(size_t)node * 32 + 2 * l]     = make_float4(o0, o1, o2, o3);
        ((float4*)outf)[(size_t)node * 32 + 2 * l + 1] = make_float4(o4, o5, o6, o7);
    } else {
        uint4 o;
        o.x = (uint)f2bf(o0) | ((uint)f2bf(o1) << 16);
        o.y = (uint)f2bf(o2) | ((uint)f2bf(o3) << 16);
        o.z = (uint)f2bf(o4) | ((uint)f2bf(o5) << 16);
        o.w = (uint)f2bf(o6) | ((uint)f2bf(o7) << 16);
        outb[(size_t)node * 16 + l] = o;
    }
}

// ---------------- launch ----------------
extern "C" void kernel_launch(void* const* d_in, const int* in_sizes, int n_in,
                              void* d_out, int out_size, void* d_ws, size_t ws_size,
                              hipStream_t stream) {
    const float* x  = (const float*)d_in[0];
    const int*   ei = (const int*)d_in[1];
    const float* W1 = (const float*)d_in[2];
    const float* b1 = (const float*)d_in[3];
    const float* W2 = (const float*)d_in[4];
    const float* b2 = (const float*)d_in[5];
    const float* g1 = (const float*)d_in[6];
    const float* be1 = (const float*)d_in[7];
    const float* g2 = (const float*)d_in[8];
    const float* be2 = (const float*)d_in[9];

    int N = in_sizes[0] / FDIM;
    int E = in_sizes[1] / 2;
    const int* srcp = ei;
    const int* dstp = ei + E;
    float* out = (float*)d_out;

    char* w = (char*)d_ws;
    size_t off = 0;
    auto take = [&](size_t bytes) {
        void* p = w + off;
        off = (off + bytes + 255) & ~(size_t)255;
        return p;
    };
    int nbk  = (N + 511) >> BSH;
    int nblk = (E + EPB - 1) / EPB;

    ushort* hb   = (ushort*)take((size_t)(N + 1) * FDIM * sizeof(ushort)); // h' + zero row N
    ushort* WT1  = (ushort*)take(128 * 128 * sizeof(ushort));
    ushort* WT2  = (ushort*)take(128 * 128 * sizeof(ushort));
    uint* mat    = (uint*)take((size_t)nblk * nbk * sizeof(uint));
    uint* btot   = (uint*)take((size_t)nbk * sizeof(uint));
    uint* padtot = (uint*)take((size_t)nbk * sizeof(uint));
    uint* ebuf   = (uint*)take((size_t)E * sizeof(uint));
    int* deg     = (int*)take((size_t)N * sizeof(int));
    int* rowptr  = (int*)take((size_t)(N + 1) * sizeof(int));
    int* colb    = (int*)take((size_t)(E + 15 * (size_t)N + 1024) * sizeof(int)); // pad-16
    float* dinv  = (float*)take((size_t)N * sizeof(float));
    (void)ws_size;

    int ngemm = (N + 63) / 64;

    // zero sentinel row N of hb
    hipMemsetAsync(hb + (size_t)N * FDIM, 0, FDIM * sizeof(ushort), stream);

    // weights -> W^T bf16
    k_wt2<<<256, 128, 0, stream>>>(W1, W2, WT1, WT2);

    // bucketed CSR build (no global atomics)
    k_bcount<<<nblk, 256, 0, stream>>>(dstp, mat, nbk, E);
    k_colscan<<<nbk, 1024, 0, stream>>>(mat, btot, nbk, nblk);
    k_bscatter<<<nblk, 256, 0, stream>>>(srcp, dstp, mat, btot, ebuf, nbk, E);
    k_bdeg<<<nbk, 256, 0, stream>>>(ebuf, btot, deg, dinv, padtot, N, nbk);

    // MEGA: gemm1 (fp32 in, convert + dinv-scale fused) || D2 bucket fill
    k_mega<<<ngemm + nbk, 256, 0, stream>>>(x, WT1, dinv, hb, N, ngemm,
                                            ebuf, btot, padtot, deg, rowptr, colb, nbk);

    // layer 1 agg (bf16 out into d_out front)
    k_agg<<<(N + 15) / 16, 256, 0, stream>>>((const uint4*)hb, rowptr, colb, dinv,
                                             b1, g1, be1, nullptr, (uint4*)d_out, N);
    // layer 2: gemm reads bf16 from d_out, agg writes final fp32 d_out
    k_gemm<false><<<ngemm, 256, 0, stream>>>(d_out, WT2, dinv, hb, N);
    k_agg<<<(N + 15) / 16, 256, 0, stream>>>((const uint4*)hb, rowptr, colb, dinv,
                                             b2, g2, be2, out, nullptr, N);
}

// Round 17
// 220.600 us; speedup vs baseline: 1.2946x; 1.0132x over previous
//
#include <hip/hip_runtime.h>

#define FDIM 128
#define LN_EPS 1e-5f
#define BSH 9              // 512 nodes per bucket
#define EPB 2048           // edges per block in bucket passes

typedef short short8 __attribute__((ext_vector_type(8)));
typedef float f32x4 __attribute__((ext_vector_type(4)));

__device__ __forceinline__ ushort f2bf(float f) {
    uint u = __float_as_uint(f);
    u += 0x7fff + ((u >> 16) & 1);      // RNE
    return (ushort)(u >> 16);
}
__device__ __forceinline__ float bflo(uint u) { return __uint_as_float(u << 16); }
__device__ __forceinline__ float bfhi(uint u) { return __uint_as_float(u & 0xffff0000u); }

// ---------------- bucketed CSR build (no global atomics) — proven R12 ----------------
__global__ __launch_bounds__(256) void k_bcount(const int* __restrict__ dst,
                                                uint* __restrict__ mat, int nbk, int E) {
    __shared__ uint cnt[512];
    int t = threadIdx.x;
    for (int i = t; i < nbk; i += 256) cnt[i] = 0;
    __syncthreads();
    int base = blockIdx.x * EPB, end = min(base + EPB, E);
    for (int e = base + t; e < end; e += 256)
        atomicAdd(&cnt[(uint)dst[e] >> BSH], 1u);
    __syncthreads();
    for (int i = t; i < nbk; i += 256) mat[(size_t)blockIdx.x * nbk + i] = cnt[i];
}

__global__ __launch_bounds__(1024) void k_colscan(uint* __restrict__ mat,
                                                  uint* __restrict__ btot, int nbk, int nblk) {
    __shared__ uint s[1024];
    int b = blockIdx.x, t = threadIdx.x;
    uint run = 0;
    for (int base = 0; base < nblk; base += 1024) {
        int i = base + t;
        uint v = (i < nblk) ? mat[(size_t)i * nbk + b] : 0;
        s[t] = v;
        __syncthreads();
        for (int off = 1; off < 1024; off <<= 1) {
            uint u = (t >= off) ? s[t - off] : 0;
            __syncthreads();
            s[t] += u;
            __syncthreads();
        }
        if (i < nblk) mat[(size_t)i * nbk + b] = run + s[t] - v;
        run += s[1023];
        __syncthreads();
    }
    if (t == 0) btot[b] = run;
}

__global__ __launch_bounds__(256) void k_bscatter(const int* __restrict__ src,
                                                  const int* __restrict__ dst,
                                                  const uint* __restrict__ mat,
                                                  const uint* __restrict__ btot,
                                                  uint* __restrict__ ebuf, int nbk, int E) {
    __shared__ uint cur[512];
    __shared__ uint ps[256];
    int t = threadIdx.x;
    uint v = (t < nbk) ? btot[t] : 0;
    ps[t] = v;
    __syncthreads();
    for (int off = 1; off < 256; off <<= 1) {
        uint u = (t >= off) ? ps[t - off] : 0;
        __syncthreads();
        ps[t] += u;
        __syncthreads();
    }
    if (t < nbk) cur[t] = (ps[t] - v) + mat[(size_t)blockIdx.x * nbk + t];
    __syncthreads();
    int base = blockIdx.x * EPB, end = min(base + EPB, E);
    for (int e = base + t; e < end; e += 256) {
        uint d = (uint)dst[e];
        uint off = atomicAdd(&cur[d >> BSH], 1u);
        ebuf[off] = ((d & 511u) << 17) | (uint)src[e];
    }
}

__global__ __launch_bounds__(256) void k_bdeg(const uint* __restrict__ ebuf,
                                              const uint* __restrict__ btot,
                                              int* __restrict__ deg, float* __restrict__ dinv,
                                              uint* __restrict__ padtot, int N, int nbk) {
    __shared__ uint cnt[512];
    __shared__ uint ps[256];
    __shared__ uint begs;
    int b = blockIdx.x, t = threadIdx.x;
    for (int i = t; i < 512; i += 256) cnt[i] = 0;
    uint v = (t < nbk) ? btot[t] : 0;
    ps[t] = v;
    __syncthreads();
    for (int off = 1; off < 256; off <<= 1) {
        uint u = (t >= off) ? ps[t - off] : 0;
        __syncthreads();
        ps[t] += u;
        __syncthreads();
    }
    if (t == b) begs = ps[t] - v;
    __syncthreads();
    uint beg = begs, cn = btot[b];
    for (uint i = t; i < cn; i += 256) atomicAdd(&cnt[ebuf[beg + i] >> 17], 1u);
    __syncthreads();
    int n0 = b << BSH;
    uint loc = 0;
    for (int i = t; i < 512; i += 256) {
        int n = n0 + i;
        if (n < N) {
            uint dg = cnt[i];
            deg[n] = (int)dg;
            dinv[n] = rsqrtf((float)dg + 1.0f);
            loc += (dg + 7u) & ~7u;
        }
    }
    ps[t] = loc;
    __syncthreads();
    for (int off = 128; off >= 1; off >>= 1) {
        if (t < off) ps[t] += ps[t + off];
        __syncthreads();
    }
    if (t == 0) padtot[b] = ps[0];
}

__device__ __forceinline__ void bfill_body(const uint* __restrict__ ebuf,
                                           const uint* __restrict__ btot,
                                           const uint* __restrict__ padtot,
                                           const int* __restrict__ deg,
                                           int* __restrict__ rowptr, int* __restrict__ col,
                                           int N, int nbk, int b) {
    __shared__ uint ps[256];
    __shared__ uint curf[512];
    __shared__ uint sc0, sc1;
    int t = threadIdx.x;
    uint v = (t < nbk) ? btot[t] : 0;
    ps[t] = v;
    __syncthreads();
    for (int off = 1; off < 256; off <<= 1) {
        uint u = (t >= off) ? ps[t - off] : 0;
        __syncthreads();
        ps[t] += u;
        __syncthreads();
    }
    if (t == b) sc0 = ps[t] - v;
    __syncthreads();
    uint w = (t < nbk) ? padtot[t] : 0;
    ps[t] = w;
    __syncthreads();
    for (int off = 1; off < 256; off <<= 1) {
        uint u = (t >= off) ? ps[t - off] : 0;
        __syncthreads();
        ps[t] += u;
        __syncthreads();
    }
    if (t == b) sc1 = ps[t] - w;
    if (b == nbk - 1 && t == nbk - 1) rowptr[N] = (int)ps[t];
    __syncthreads();
    uint beg = sc0, cn = btot[b], base = sc1;
    int n0 = b << BSH;
    int nA = n0 + 2 * t, nB = nA + 1;
    uint dA = (nA < N) ? (uint)deg[nA] : 0;
    uint dB = (nB < N) ? (uint)deg[nB] : 0;
    uint pA = (dA + 7u) & ~7u, pB = (dB + 7u) & ~7u;
    uint pair = pA + pB;
    ps[t] = pair;
    __syncthreads();
    for (int off = 1; off < 256; off <<= 1) {
        uint u = (t >= off) ? ps[t - off] : 0;
        __syncthreads();
        ps[t] += u;
        __syncthreads();
    }
    uint pex = ps[t] - pair;
    uint rA = base + pex, rB = rA + pA;
    curf[2 * t] = rA; curf[2 * t + 1] = rB;
    if (nA < N) rowptr[nA] = (int)rA;
    if (nB < N) rowptr[nB] = (int)rB;
    if (nA < N) for (uint k = dA; k < pA; ++k) col[rA + k] = N;
    if (nB < N) for (uint k = dB; k < pB; ++k) col[rB + k] = N;
    __syncthreads();
    for (uint i = t; i < cn; i += 256) {
        uint e = ebuf[beg + i];
        uint p = atomicAdd(&curf[e >> 17], 1u);
        col[p] = (int)(e & 0x1FFFFu);
    }
}

// ---------------- W[128,128] fp32 -> W^T bf16 (both weights, one launch) ----------------
__global__ void k_wt2(const float* __restrict__ W1, const float* __restrict__ W2,
                      ushort* __restrict__ WT1, ushort* __restrict__ WT2) {
    int b = blockIdx.x, k = threadIdx.x;
    if (b < 128) WT1[b * 128 + k] = f2bf(W1[k * 128 + b]);
    else         WT2[(b - 128) * 128 + k] = f2bf(W2[k * 128 + (b - 128)]);
}

// -------- GEMM body: H'[r] = dinv[r] * (X[r,:] @ W)  (bf16 out, pre-scaled) --------
template <bool F32IN>
__device__ __forceinline__ void gemm_body(char* sXb, char* sWb,
                                          const void* __restrict__ Xin,
                                          const ushort* __restrict__ WT,
                                          const float* __restrict__ dinv,
                                          ushort* __restrict__ H, int N, int bid) {
    int t = threadIdx.x;
    int w = t >> 6, lane = t & 63;
    int cl = lane & 15, kq = lane >> 4;
    int base = bid * 64;

    const short8* Wg = (const short8*)WT;
#pragma unroll
    for (int k = 0; k < 8; ++k) {
        int idx = t + k * 256;
        int c = idx >> 4, ch = idx & 15;
        *(short8*)(sWb + c * 256 + ((ch * 16) ^ ((c & 7) << 4))) = Wg[idx];
    }

    if constexpr (F32IN) {
        const float4* X4 = (const float4*)Xin;
        size_t lim = (size_t)N * 32 - 1;
#pragma unroll
        for (int k = 0; k < 8; ++k) {
            int idx = t + k * 256;
            size_t gi = (size_t)base * 32 + idx;
            float4 v = X4[gi < lim ? gi : lim];
            ushort4 o;
            o.x = f2bf(v.x); o.y = f2bf(v.y); o.z = f2bf(v.z); o.w = f2bf(v.w);
            int row = idx >> 5, b8 = (idx & 31) * 8;
            *(ushort4*)(sXb + row * 256 + (b8 ^ ((row & 7) << 4))) = o;
        }
    } else {
        const short8* X8 = (const short8*)Xin;
        size_t lim = (size_t)N * 16 - 1;
#pragma unroll
        for (int k = 0; k < 4; ++k) {
            int idx = t + k * 256;
            size_t gi = (size_t)base * 16 + idx;
            short8 v = X8[gi < lim ? gi : lim];
            int row = idx >> 4, b16 = (idx & 15) * 16;
            *(short8*)(sXb + row * 256 + (b16 ^ ((row & 7) << 4))) = v;
        }
    }
    __syncthreads();

    int rl = w * 16 + cl;
    short8 b0, b1, b2, b3;
#pragma unroll
    for (int kt = 0; kt < 4; ++kt) {
        short8 v = *(const short8*)(sXb + rl * 256 + ((kt * 64 + kq * 16) ^ ((rl & 7) << 4)));
        if (kt == 0) b0 = v; else if (kt == 1) b1 = v; else if (kt == 2) b2 = v; else b3 = v;
    }

    int r = base + rl;
    bool ok = r < N;
    float di = dinv[min(r, N - 1)];
#pragma unroll
    for (int nt = 0; nt < 8; ++nt) {
        int c = nt * 16 + cl;
        int sw = (c & 7) << 4;
        f32x4 acc = {0.f, 0.f, 0.f, 0.f};
        acc = __builtin_amdgcn_mfma_f32_16x16x32_bf16(
            *(const short8*)(sWb + c * 256 + ((0 * 64 + kq * 16) ^ sw)), b0, acc, 0, 0, 0);
        acc = __builtin_amdgcn_mfma_f32_16x16x32_bf16(
            *(const short8*)(sWb + c * 256 + ((1 * 64 + kq * 16) ^ sw)), b1, acc, 0, 0, 0);
        acc = __builtin_amdgcn_mfma_f32_16x16x32_bf16(
            *(const short8*)(sWb + c * 256 + ((2 * 64 + kq * 16) ^ sw)), b2, acc, 0, 0, 0);
        acc = __builtin_amdgcn_mfma_f32_16x16x32_bf16(
            *(const short8*)(sWb + c * 256 + ((3 * 64 + kq * 16) ^ sw)), b3, acc, 0, 0, 0);
        if (ok) {
            ushort4 o;
            o.x = f2bf(acc[0] * di); o.y = f2bf(acc[1] * di);
            o.z = f2bf(acc[2] * di); o.w = f2bf(acc[3] * di);
            *(ushort4*)(H + (size_t)r * 128 + nt * 16 + kq * 4) = o;
        }
    }
}

// standalone gemm (layer 2)
template <bool F32IN>
__global__ __launch_bounds__(256) void k_gemm(const void* __restrict__ Xin,
                                              const ushort* __restrict__ WT,
                                              const float* __restrict__ dinv,
                                              ushort* __restrict__ H, int N) {
    __shared__ ushort sX[64 * 128];
    __shared__ ushort sW[128 * 128];
    gemm_body<F32IN>((char*)sX, (char*)sW, Xin, WT, dinv, H, N, blockIdx.x);
}

// -------- MEGA: blocks [0,ngemm) = gemm1 (fp32 in), blocks [ngemm,ngemm+nbk) = D2 fill --------
__global__ __launch_bounds__(256) void k_mega(const void* __restrict__ Xin,
                                              const ushort* __restrict__ WT,
                                              const float* __restrict__ dinv,
                                              ushort* __restrict__ H, int N, int ngemm,
                                              const uint* __restrict__ ebuf,
                                              const uint* __restrict__ btot,
                                              const uint* __restrict__ padtot,
                                              const int* __restrict__ deg,
                                              int* __restrict__ rowptr,
                                              int* __restrict__ col, int nbk) {
    __shared__ ushort sX[64 * 128];
    __shared__ ushort sW[128 * 128];
    if (blockIdx.x < (uint)ngemm) {
        gemm_body<true>((char*)sX, (char*)sW, Xin, WT, dinv, H, N, blockIdx.x);
    } else {
        bfill_body(ebuf, btot, padtot, deg, rowptr, col, N, nbk, blockIdx.x - ngemm);
    }
}

// ------- aggregate(pre-scaled bf16 h') + bias + ReLU + LN -------
// 4 nodes/wave (16 lanes each, uint4 = 8 features/lane), pad-8 rows (no clamps);
// quarters exec-mask-diverge on their own deg8.
__global__ __launch_bounds__(256) void k_agg(const uint4* __restrict__ H4,  // (N+1) rows x 16 uint4
                                             const int* __restrict__ rowptr, // rounded-8
                                             const int* __restrict__ col,
                                             const float* __restrict__ dinv,
                                             const float* __restrict__ bias,
                                             const float* __restrict__ gamma,
                                             const float* __restrict__ beta,
                                             float* __restrict__ outf,
                                             uint4* __restrict__ outb,
                                             int N) {
    int wave = threadIdx.x >> 6;
    int lane = threadIdx.x & 63;
    int q = lane >> 4;
    int l = lane & 15;
    int node = blockIdx.x * 16 + wave * 4 + q;
    bool valid = node < N;
    int nodec = valid ? node : N - 1;

    float di = dinv[nodec];
    uint4 hs = H4[(uint)nodec * 16u + (uint)l];
    float a0 = bflo(hs.x), a1 = bfhi(hs.x), a2 = bflo(hs.y), a3 = bfhi(hs.y);
    float a4 = bflo(hs.z), a5 = bfhi(hs.z), a6 = bflo(hs.w), a7 = bfhi(hs.w);

    int beg = rowptr[nodec];
    int deg8 = rowptr[nodec + 1] - beg;
    const int* cp = col + beg;

    for (int i = 0; i < deg8; i += 8) {
        int s0 = cp[i + 0], s1 = cp[i + 1], s2 = cp[i + 2], s3 = cp[i + 3];
        int s4 = cp[i + 4], s5 = cp[i + 5], s6 = cp[i + 6], s7 = cp[i + 7];
        uint4 u0 = H4[(uint)s0 * 16u + (uint)l];
        uint4 u1 = H4[(uint)s1 * 16u + (uint)l];
        uint4 u2 = H4[(uint)s2 * 16u + (uint)l];
        uint4 u3 = H4[(uint)s3 * 16u + (uint)l];
        uint4 u4 = H4[(uint)s4 * 16u + (uint)l];
        uint4 u5 = H4[(uint)s5 * 16u + (uint)l];
        uint4 u6 = H4[(uint)s6 * 16u + (uint)l];
        uint4 u7 = H4[(uint)s7 * 16u + (uint)l];
        a0 += bflo(u0.x); a1 += bfhi(u0.x); a2 += bflo(u0.y); a3 += bfhi(u0.y);
        a4 += bflo(u0.z); a5 += bfhi(u0.z); a6 += bflo(u0.w); a7 += bfhi(u0.w);
        a0 += bflo(u1.x); a1 += bfhi(u1.x); a2 += bflo(u1.y); a3 += bfhi(u1.y);
        a4 += bflo(u1.z); a5 += bfhi(u1.z); a6 += bflo(u1.w); a7 += bfhi(u1.w);
        a0 += bflo(u2.x); a1 += bfhi(u2.x); a2 += bflo(u2.y); a3 += bfhi(u2.y);
        a4 += bflo(u2.z); a5 += bfhi(u2.z); a6 += bflo(u2.w); a7 += bfhi(u2.w);
        a0 += bflo(u3.x); a1 += bfhi(u3.x); a2 += bflo(u3.y); a3 += bfhi(u3.y);
        a4 += bflo(u3.z); a5 += bfhi(u3.z); a6 += bflo(u3.w); a7 += bfhi(u3.w);
        a0 += bflo(u4.x); a1 += bfhi(u4.x); a2 += bflo(u4.y); a3 += bfhi(u4.y);
        a4 += bflo(u4.z); a5 += bfhi(u4.z); a6 += bflo(u4.w); a7 += bfhi(u4.w);
        a0 += bflo(u5.x); a1 += bfhi(u5.x); a2 += bflo(u5.y); a3 += bfhi(u5.y);
        a4 += bflo(u5.z); a5 += bfhi(u5.z); a6 += bflo(u5.w); a7 += bfhi(u5.w);
        a0 += bflo(u6.x); a1 += bfhi(u6.x); a2 += bflo(u6.y); a3 += bfhi(u6.y);
        a4 += bflo(u6.z); a5 += bfhi(u6.z); a6 += bflo(u6.w); a7 += bfhi(u6.w);
        a0 += bflo(u7.x); a1 += bfhi(u7.x); a2 += bflo(u7.y); a3 += bfhi(u7.y);
        a4 += bflo(u7.z); a5 += bfhi(u7.z); a6 += bflo(u7.w); a7 += bfhi(u7.w);
    }

    float4 bb0 = ((const float4*)bias)[2 * l];
    float4 bb1 = ((const float4*)bias)[2 * l + 1];
    a0 = fmaxf(fmaf(a0, di, bb0.x), 0.f);
    a1 = fmaxf(fmaf(a1, di, bb0.y), 0.f);
    a2 = fmaxf(fmaf(a2, di, bb0.z), 0.f);
    a3 = fmaxf(fmaf(a3, di, bb0.w), 0.f);
    a4 = fmaxf(fmaf(a4, di, bb1.x), 0.f);
    a5 = fmaxf(fmaf(a5, di, bb1.y), 0.f);
    a6 = fmaxf(fmaf(a6, di, bb1.z), 0.f);
    a7 = fmaxf(fmaf(a7, di, bb1.w), 0.f);

    float s1 = ((a0 + a1) + (a2 + a3)) + ((a4 + a5) + (a6 + a7));
    float s2 = ((a0 * a0 + a1 * a1) + (a2 * a2 + a3 * a3)) +
               ((a4 * a4 + a5 * a5) + (a6 * a6 + a7 * a7));
#pragma unroll
    for (int off = 8; off >= 1; off >>= 1) {
        s1 += __shfl_xor(s1, off);
        s2 += __shfl_xor(s2, off);
    }
    float mu = s1 * (1.f / 128.f);
    float var = s2 * (1.f / 128.f) - mu * mu;
    float rs = rsqrtf(var + LN_EPS);

    float4 g0 = ((const float4*)gamma)[2 * l];
    float4 g1 = ((const float4*)gamma)[2 * l + 1];
    float4 e0 = ((const float4*)beta)[2 * l];
    float4 e1 = ((const float4*)beta)[2 * l + 1];
    float o0 = (a0 - mu) * rs * g0.x + e0.x;
    float o1 = (a1 - mu) * rs * g0.y + e0.y;
    float o2 = (a2 - mu) * rs * g0.z + e0.z;
    float o3 = (a3 - mu) * rs * g0.w + e0.w;
    float o4 = (a4 - mu) * rs * g1.x + e1.x;
    float o5 = (a5 - mu) * rs * g1.y + e1.y;
    float o6 = (a6 - mu) * rs * g1.z + e1.z;
    float o7 = (a7 - mu) * rs * g1.w + e1.w;

    if (!valid) return;
    if (outf) {
        ((float4*)outf)[(size_t)node * 32 + 2 * l]     = make_float4(o0, o1, o2, o3);
        ((float4*)outf)[(size_t)node * 32 + 2 * l + 1] = make_float4(o4, o5, o6, o7);
    } else {
        uint4 o;
        o.x = (uint)f2bf(o0) | ((uint)f2bf(o1) << 16);
        o.y = (uint)f2bf(o2) | ((uint)f2bf(o3) << 16);
        o.z = (uint)f2bf(o4) | ((uint)f2bf(o5) << 16);
        o.w = (uint)f2bf(o6) | ((uint)f2bf(o7) << 16);
        outb[(size_t)node * 16 + l] = o;
    }
}

// ---------------- launch ----------------
extern "C" void kernel_launch(void* const* d_in, const int* in_sizes, int n_in,
                              void* d_out, int out_size, void* d_ws, size_t ws_size,
                              hipStream_t stream) {
    const float* x  = (const float*)d_in[0];
    const int*   ei = (const int*)d_in[1];
    const float* W1 = (const float*)d_in[2];
    const float* b1 = (const float*)d_in[3];
    const float* W2 = (const float*)d_in[4];
    const float* b2 = (const float*)d_in[5];
    const float* g1 = (const float*)d_in[6];
    const float* be1 = (const float*)d_in[7];
    const float* g2 = (const float*)d_in[8];
    const float* be2 = (const float*)d_in[9];

    int N = in_sizes[0] / FDIM;
    int E = in_sizes[1] / 2;
    const int* srcp = ei;
    const int* dstp = ei + E;
    float* out = (float*)d_out;

    char* w = (char*)d_ws;
    size_t off = 0;
    auto take = [&](size_t bytes) {
        void* p = w + off;
        off = (off + bytes + 255) & ~(size_t)255;
        return p;
    };
    int nbk  = (N + 511) >> BSH;
    int nblk = (E + EPB - 1) / EPB;

    ushort* hb   = (ushort*)take((size_t)(N + 1) * FDIM * sizeof(ushort)); // h' + zero row N
    ushort* WT1  = (ushort*)take(128 * 128 * sizeof(ushort));
    ushort* WT2  = (ushort*)take(128 * 128 * sizeof(ushort));
    uint* mat    = (uint*)take((size_t)nblk * nbk * sizeof(uint));
    uint* btot   = (uint*)take((size_t)nbk * sizeof(uint));
    uint* padtot = (uint*)take((size_t)nbk * sizeof(uint));
    uint* ebuf   = (uint*)take((size_t)E * sizeof(uint));
    int* deg     = (int*)take((size_t)N * sizeof(int));
    int* rowptr  = (int*)take((size_t)(N + 1) * sizeof(int));
    int* colb    = (int*)take((size_t)(E + 7 * (size_t)N + 1024) * sizeof(int));
    float* dinv  = (float*)take((size_t)N * sizeof(float));
    (void)ws_size;

    int ngemm = (N + 63) / 64;

    // zero sentinel row N of hb
    hipMemsetAsync(hb + (size_t)N * FDIM, 0, FDIM * sizeof(ushort), stream);

    // weights -> W^T bf16
    k_wt2<<<256, 128, 0, stream>>>(W1, W2, WT1, WT2);

    // bucketed CSR build (no global atomics)
    k_bcount<<<nblk, 256, 0, stream>>>(dstp, mat, nbk, E);
    k_colscan<<<nbk, 1024, 0, stream>>>(mat, btot, nbk, nblk);
    k_bscatter<<<nblk, 256, 0, stream>>>(srcp, dstp, mat, btot, ebuf, nbk, E);
    k_bdeg<<<nbk, 256, 0, stream>>>(ebuf, btot, deg, dinv, padtot, N, nbk);

    // MEGA: gemm1 (fp32 in, convert + dinv-scale fused) || D2 bucket fill
    k_mega<<<ngemm + nbk, 256, 0, stream>>>(x, WT1, dinv, hb, N, ngemm,
                                            ebuf, btot, padtot, deg, rowptr, colb, nbk);

    // layer 1 agg (bf16 out into d_out front)
    k_agg<<<(N + 15) / 16, 256, 0, stream>>>((const uint4*)hb, rowptr, colb, dinv,
                                             b1, g1, be1, nullptr, (uint4*)d_out, N);
    // layer 2: gemm reads bf16 from d_out, agg writes final fp32 d_out
    k_gemm<false><<<ngemm, 256, 0, stream>>>(d_out, WT2, dinv, hb, N);
    k_agg<<<(N + 15) / 16, 256, 0, stream>>>((const uint4*)hb, rowptr, colb, dinv,
                                             b2, g2, be2, out, nullptr, N);
}